// Round 3
// baseline (449.081 us; speedup 1.0000x reference)
//
#include <hip/hip_runtime.h>

typedef unsigned short u16;
typedef unsigned int u32;
typedef short bf16x8 __attribute__((ext_vector_type(8)));
typedef float f32x4 __attribute__((ext_vector_type(4)));

constexpr int Bb = 2, Cc = 1024, Tt = 2048, Hh = 16, Dd = 64;

__device__ __forceinline__ u16 f2bf(float f) {
    union { float f; u32 i; } c; c.f = f;
    u32 u = c.i;
    u32 r = (u + 0x7FFFu + ((u >> 16) & 1u)) >> 16;
    return (u16)r;
}
// pack two fp32 -> bf16x2 (round-half-up; plenty of headroom vs 2e-2 threshold)
__device__ __forceinline__ u32 pk_bf2(float lo, float hi) {
    union { float f; u32 i; } a, b; a.f = lo; b.f = hi;
    u32 ua = a.i + 0x8000u, ub = b.i + 0x8000u;
    return (ub & 0xFFFF0000u) | (ua >> 16);
}

// ---------------- fp32 -> bf16 elementwise (weights) ----------------
__global__ __launch_bounds__(256) void cvt_bf16(const float* __restrict__ in,
                                                u16* __restrict__ out, int n) {
    int i = (blockIdx.x * 256 + threadIdx.x) * 4;
    if (i + 3 < n) {
        float4 v = *(const float4*)(in + i);
        out[i + 0] = f2bf(v.x);
        out[i + 1] = f2bf(v.y);
        out[i + 2] = f2bf(v.z);
        out[i + 3] = f2bf(v.w);
    }
}

// ---------------- x transpose+convert: fp32 [b][c][t] -> bf16 [b][t][c] ----------------
__global__ __launch_bounds__(256) void transpose_x(const float* __restrict__ x,
                                                   u16* __restrict__ xT) {
    __shared__ u16 tile[32][33];
    int b = blockIdx.z;
    int t0 = blockIdx.x * 32, c0 = blockIdx.y * 32;
    int tx = threadIdx.x, ty = threadIdx.y;
    const float* xb = x + (size_t)b * Cc * Tt;
    u16* xTb = xT + (size_t)b * Tt * Cc;
#pragma unroll
    for (int i = 0; i < 4; i++) {
        int r = ty + i * 8;
        tile[r][tx] = f2bf(xb[(size_t)(c0 + r) * Tt + t0 + tx]);
    }
    __syncthreads();
#pragma unroll
    for (int i = 0; i < 4; i++) {
        int r = ty + i * 8;
        xTb[(size_t)(t0 + r) * Cc + c0 + tx] = tile[tx][r];
    }
}

// ---------------- GEMM: D[m,n] = sum_k A[m,k]*Bt[n,k] + bias[n] ----------------
__global__ __launch_bounds__(256) void gemm_bt(const u16* __restrict__ A,
                                               const u16* __restrict__ Bt,
                                               const float* __restrict__ bias,
                                               const int* __restrict__ mask,
                                               void* __restrict__ outv, int mode) {
    constexpr int M = Tt, K = Cc;
    __shared__ u16 Alds[64][40];
    __shared__ u16 Blds[64][40];
    int b = blockIdx.z;
    int n0 = blockIdx.x * 64, m0 = blockIdx.y * 64;
    int tid = threadIdx.x;
    int lane = tid & 63, wave = tid >> 6;
    int quad = lane >> 4, id15 = lane & 15;
    int wm = (wave & 1) * 32, wn = (wave >> 1) * 32;
    const u16* Ab = A + (size_t)b * M * K;
    int srow = tid >> 2, scg = tid & 3;

    f32x4 acc[2][2] = {};

    for (int k0 = 0; k0 < K; k0 += 32) {
        __syncthreads();
        uint4 av = *(const uint4*)(Ab + (size_t)(m0 + srow) * K + k0 + scg * 8);
        uint4 bv = *(const uint4*)(Bt + (size_t)(n0 + srow) * K + k0 + scg * 8);
        *(uint4*)(&Alds[srow][scg * 8]) = av;
        *(uint4*)(&Blds[srow][scg * 8]) = bv;
        __syncthreads();
        bf16x8 af[2], bff[2];
#pragma unroll
        for (int mi = 0; mi < 2; mi++)
            af[mi] = *(const bf16x8*)(&Alds[wm + mi * 16 + id15][quad * 8]);
#pragma unroll
        for (int ni = 0; ni < 2; ni++)
            bff[ni] = *(const bf16x8*)(&Blds[wn + ni * 16 + id15][quad * 8]);
#pragma unroll
        for (int mi = 0; mi < 2; mi++)
#pragma unroll
            for (int ni = 0; ni < 2; ni++)
                acc[mi][ni] = __builtin_amdgcn_mfma_f32_16x16x32_bf16(
                    af[mi], bff[ni], acc[mi][ni], 0, 0, 0);
    }

#pragma unroll
    for (int mi = 0; mi < 2; mi++) {
#pragma unroll
        for (int ni = 0; ni < 2; ni++) {
            int n = n0 + wn + ni * 16 + id15;
            float bvv = bias[n];
#pragma unroll
            for (int r = 0; r < 4; r++) {
                int m = m0 + wm + mi * 16 + quad * 4 + r;
                float v = acc[mi][ni][r] + bvv;
                if (mode <= 1) {
                    int h = n >> 6, d = n & 63;
                    ((u16*)outv)[(((size_t)b * Hh + h) * Tt + m) * Dd + d] = f2bf(v);
                } else if (mode == 2) {
                    int h = n >> 6, d = n & 63;
                    ((u16*)outv)[(((size_t)b * Hh + h) * Dd + d) * Tt + m] = f2bf(v);
                } else {
                    float mm = mask[b * Tt + m] ? 1.0f : 0.0f;
                    ((float*)outv)[((size_t)b * Cc + n) * Tt + m] = v * mm;
                }
            }
        }
    }
}

// ---------------- barrier-free flash attention (S^T formulation) ----------------
// q,k: [b][h][t][d] bf16 ; vT: [b][h][d][t] bf16 ; o_buf: [b][t][h*64+d] bf16
// Per wave: 16 queries. S^T = K·Q^T so query lives in lane column (i=lane&15):
// scalar m/l per lane, 4 shuffles per chunk, P-transpose via 8 ds_bpermute,
// O^T = V^T·P^T. No LDS, no __syncthreads.
__global__ __launch_bounds__(256) void attn(const u16* __restrict__ q,
                                            const u16* __restrict__ kk,
                                            const u16* __restrict__ vT,
                                            const int* __restrict__ mask,
                                            u16* __restrict__ o_buf) {
    int bh = blockIdx.y;
    int b = bh >> 4;
    int h = bh & 15;
    int t0 = blockIdx.x * 64;
    int tid = threadIdx.x;
    int lane = tid & 63, wave = tid >> 6;
    int quad = lane >> 4, id15 = lane & 15;
    int qrow = t0 + wave * 16;
    const u16* qb = q + (size_t)bh * Tt * Dd;
    const u16* kb = kk + (size_t)bh * Tt * Dd;
    const u16* vb = vT + (size_t)bh * Dd * Tt;
    const int* mrow = mask + b * Tt;

    // Q as B-operand: lane holds Q[i=id15][c=quad*8+e (+32*half)]
    bf16x8 qf[2];
#pragma unroll
    for (int hf = 0; hf < 2; hf++)
        qf[hf] = *(const bf16x8*)(qb + (size_t)(qrow + id15) * Dd + hf * 32 + quad * 8);

    float m_s = -1e30f, l_s = 0.0f;
    f32x4 accO[4] = {};

    for (int j0 = 0; j0 < Tt; j0 += 32) {
        // key mask for C rows j = j0 + jt*16 + quad*4 + r (prefetch before MFMAs)
        int4 mk0 = *(const int4*)(mrow + j0 + quad * 4);
        int4 mk1 = *(const int4*)(mrow + j0 + 16 + quad * 4);

        // S^T[j][i] = sum_c K[j][c] * Q[i][c]
        f32x4 st[2] = {};
#pragma unroll
        for (int jt = 0; jt < 2; jt++)
#pragma unroll
            for (int hf = 0; hf < 2; hf++) {
                bf16x8 kf = *(const bf16x8*)(kb + (size_t)(j0 + jt * 16 + id15) * Dd +
                                             hf * 32 + quad * 8);
                st[jt] = __builtin_amdgcn_mfma_f32_16x16x32_bf16(kf, qf[hf], st[jt], 0, 0, 0);
            }

        // scale + mask, in-lane max over 8 scores
        const int* mks[2] = { &mk0.x, &mk1.x };
        float mx = -1e30f;
#pragma unroll
        for (int jt = 0; jt < 2; jt++)
#pragma unroll
            for (int r = 0; r < 4; r++) {
                float v = mks[jt][r] ? st[jt][r] * 0.125f : -1e30f;
                st[jt][r] = v;
                mx = fmaxf(mx, v);
            }
        // cross-quad reduce (lanes id15, id15+16, id15+32, id15+48 share query i)
        mx = fmaxf(mx, __shfl_xor(mx, 16));
        mx = fmaxf(mx, __shfl_xor(mx, 32));

        float mn = fmaxf(m_s, mx);
        float alpha = __expf(m_s - mn);
        m_s = mn;

        float rs = 0.0f;
#pragma unroll
        for (int jt = 0; jt < 2; jt++)
#pragma unroll
            for (int r = 0; r < 4; r++) {
                float p = __expf(st[jt][r] - mn);
                st[jt][r] = p;
                rs += p;
            }
        rs += __shfl_xor(rs, 16);
        rs += __shfl_xor(rs, 32);
        l_s = l_s * alpha + rs;
#pragma unroll
        for (int mt = 0; mt < 4; mt++)
#pragma unroll
            for (int r = 0; r < 4; r++) accO[mt][r] *= alpha;

        // pack P to bf16x2 pairs: pk[jt][u] = keys (jt*16+quad*4+2u, +2u+1), query id15
        u32 pk[2][2];
#pragma unroll
        for (int jt = 0; jt < 2; jt++)
#pragma unroll
            for (int u = 0; u < 2; u++)
                pk[jt][u] = pk_bf2(st[jt][2 * u], st[jt][2 * u + 1]);

        // build P^T B-frag: lane(quad,id15) slot s holds keys j0+quad*8+2s,+2s+1
        union { u32 u[4]; bf16x8 v; } pf;
#pragma unroll
        for (int s = 0; s < 4; s++) {
            int src = (((quad & 1) * 2 + (s >> 1)) << 4) + id15;
            u32 v0 = (u32)__shfl((int)pk[0][s & 1], src);
            u32 v1 = (u32)__shfl((int)pk[1][s & 1], src);
            pf.u[s] = (quad < 2) ? v0 : v1;
        }

        // O^T[d][i] += sum_j V^T[d][j] * P^T[j][i]
#pragma unroll
        for (int mt = 0; mt < 4; mt++) {
            bf16x8 vf = *(const bf16x8*)(vb + (size_t)(mt * 16 + id15) * Tt + j0 + quad * 8);
            accO[mt] = __builtin_amdgcn_mfma_f32_16x16x32_bf16(vf, pf.v, accO[mt], 0, 0, 0);
        }
    }

    float inv = 1.0f / l_s;
    // accO C-layout: O^T[d = mt*16+quad*4+r][i = id15]; 4 contiguous d per lane -> uint2
#pragma unroll
    for (int mt = 0; mt < 4; mt++) {
        uint2 w;
        w.x = pk_bf2(accO[mt][0] * inv, accO[mt][1] * inv);
        w.y = pk_bf2(accO[mt][2] * inv, accO[mt][3] * inv);
        *(uint2*)(o_buf + ((size_t)b * Tt + qrow + id15) * Cc + h * Dd + mt * 16 + quad * 4) = w;
    }
}

// ---------------- mask tail of d_out (fp32 0/1) ----------------
__global__ void mask_out_k(const int* __restrict__ mask, float* __restrict__ out) {
    int i = blockIdx.x * 256 + threadIdx.x;
    if (i < Bb * Tt) out[i] = mask[i] ? 1.0f : 0.0f;
}

extern "C" void kernel_launch(void* const* d_in, const int* in_sizes, int n_in,
                              void* d_out, int out_size, void* d_ws, size_t ws_size,
                              hipStream_t stream) {
    const float* x  = (const float*)d_in[0];
    const int* mask = (const int*)d_in[1];
    const float* Wq = (const float*)d_in[2];
    const float* bq = (const float*)d_in[3];
    const float* Wk = (const float*)d_in[4];
    const float* bk = (const float*)d_in[5];
    const float* Wv = (const float*)d_in[6];
    const float* bv = (const float*)d_in[7];
    const float* Wp = (const float*)d_in[8];
    const float* bp = (const float*)d_in[9];
    float* out = (float*)d_out;

    size_t sz = (size_t)Bb * Tt * Cc;  // elements per activation buffer
    size_t wsz = (size_t)Cc * Cc;      // elements per weight matrix
    u16* xT = (u16*)d_ws;
    u16* qb = xT + sz;
    u16* kb = qb + sz;
    u16* vT = kb + sz;
    u16* wq16 = vT + sz;
    u16* wk16 = wq16 + wsz;
    u16* wv16 = wk16 + wsz;
    u16* wp16 = wv16 + wsz;
    u16* ob = xT;  // reuse xT: last read by V gemm, attn writes after (stream-ordered)

    int cvb = (int)(wsz / 4 / 256);
    cvt_bf16<<<cvb, 256, 0, stream>>>(Wq, wq16, (int)wsz);
    cvt_bf16<<<cvb, 256, 0, stream>>>(Wk, wk16, (int)wsz);
    cvt_bf16<<<cvb, 256, 0, stream>>>(Wv, wv16, (int)wsz);
    cvt_bf16<<<cvb, 256, 0, stream>>>(Wp, wp16, (int)wsz);
    transpose_x<<<dim3(Tt / 32, Cc / 32, Bb), dim3(32, 8), 0, stream>>>(x, xT);
    gemm_bt<<<dim3(Cc / 64, Tt / 64, Bb), 256, 0, stream>>>(xT, wq16, bq, nullptr, qb, 0);
    gemm_bt<<<dim3(Cc / 64, Tt / 64, Bb), 256, 0, stream>>>(xT, wk16, bk, nullptr, kb, 1);
    gemm_bt<<<dim3(Cc / 64, Tt / 64, Bb), 256, 0, stream>>>(xT, wv16, bv, nullptr, vT, 2);
    attn<<<dim3(Tt / 64, Bb * Hh), 256, 0, stream>>>(qb, kb, vT, mask, ob);
    gemm_bt<<<dim3(Cc / 64, Tt / 64, Bb), 256, 0, stream>>>(ob, wp16, bp, mask, out, 3);
    if (out_size >= Bb * Cc * Tt + Bb * Tt)
        mask_out_k<<<dim3((Bb * Tt + 255) / 256), 256, 0, stream>>>(
            mask, out + (size_t)Bb * Cc * Tt);
}

// Round 4
// 430.041 us; speedup vs baseline: 1.0443x; 1.0443x over previous
//
#include <hip/hip_runtime.h>

typedef unsigned short u16;
typedef unsigned int u32;
typedef short bf16x8 __attribute__((ext_vector_type(8)));
typedef float f32x4 __attribute__((ext_vector_type(4)));

constexpr int Bb = 2, Cc = 1024, Tt = 2048, Hh = 16, Dd = 64;

__device__ __forceinline__ u16 f2bf(float f) {
    union { float f; u32 i; } c; c.f = f;
    u32 u = c.i;
    u32 r = (u + 0x7FFFu + ((u >> 16) & 1u)) >> 16;
    return (u16)r;
}
// pack two fp32 -> bf16x2 (round-half-up)
__device__ __forceinline__ u32 pk_bf2(float lo, float hi) {
    union { float f; u32 i; } a, b; a.f = lo; b.f = hi;
    u32 ua = a.i + 0x8000u, ub = b.i + 0x8000u;
    return (ub & 0xFFFF0000u) | (ua >> 16);
}
// async global->LDS, 16B/lane; lds base must be wave-uniform (lane L lands at base+16L)
__device__ __forceinline__ void gl_lds16(const u16* g, u16* l) {
    __builtin_amdgcn_global_load_lds(
        (const __attribute__((address_space(1))) u32*)(const void*)g,
        (__attribute__((address_space(3))) u32*)(void*)l, 16, 0, 0);
}

// ---------------- fp32 -> bf16 elementwise (weights) ----------------
__global__ __launch_bounds__(256) void cvt_bf16(const float* __restrict__ in,
                                                u16* __restrict__ out, int n) {
    int i = (blockIdx.x * 256 + threadIdx.x) * 4;
    if (i + 3 < n) {
        float4 v = *(const float4*)(in + i);
        out[i + 0] = f2bf(v.x);
        out[i + 1] = f2bf(v.y);
        out[i + 2] = f2bf(v.z);
        out[i + 3] = f2bf(v.w);
    }
}

// ---------------- x transpose+convert: fp32 [b][c][t] -> bf16 [b][t][c] ----------------
__global__ __launch_bounds__(256) void transpose_x(const float* __restrict__ x,
                                                   u16* __restrict__ xT) {
    __shared__ u16 tile[32][33];
    int b = blockIdx.z;
    int t0 = blockIdx.x * 32, c0 = blockIdx.y * 32;
    int tx = threadIdx.x, ty = threadIdx.y;
    const float* xb = x + (size_t)b * Cc * Tt;
    u16* xTb = xT + (size_t)b * Tt * Cc;
#pragma unroll
    for (int i = 0; i < 4; i++) {
        int r = ty + i * 8;
        tile[r][tx] = f2bf(xb[(size_t)(c0 + r) * Tt + t0 + tx]);
    }
    __syncthreads();
#pragma unroll
    for (int i = 0; i < 4; i++) {
        int r = ty + i * 8;
        xTb[(size_t)(t0 + r) * Cc + c0 + tx] = tile[tx][r];
    }
}

// ---------------- 128x128x32 GEMM, global_load_lds staging (m97 structure) ----------------
// A: per-batch [2048][1024] bf16 row-major; Bt: [N][1024] bf16 row-major.
// mode 0: N=3072 fused QKV -> qb/kb (b,h,t,d) and vT (b,h,d,t), bias by section
// mode 1: N=1024 proj -> out fp32 [b][n][t] = (acc+b0[n]) * mask[b][t]
__global__ __launch_bounds__(256) void gemm128(const u16* __restrict__ A,
                                               const u16* __restrict__ Bt,
                                               const float* __restrict__ b0,
                                               const float* __restrict__ b1,
                                               const float* __restrict__ b2,
                                               const int* __restrict__ mask,
                                               u16* __restrict__ qb, u16* __restrict__ kb,
                                               u16* __restrict__ vT, float* __restrict__ out,
                                               int mode) {
    constexpr int K = Cc;
    __shared__ u16 Alds[128 * 32];
    __shared__ u16 Blds[128 * 32];
    int b = blockIdx.z;
    int n0 = blockIdx.x * 128, m0 = blockIdx.y * 128;
    int tid = threadIdx.x;
    int lane = tid & 63, wave = tid >> 6;
    int quad = lane >> 4, id15 = lane & 15;
    int wm0 = (wave & 1) * 64, wn0 = (wave >> 1) * 64;
    const u16* Ab = A + (size_t)b * Tt * K;
    int lrow = lane >> 2, lcol = (lane & 3) * 8;  // 16 rows x 4 colgroups per wave-KB

    f32x4 acc[4][4] = {};

    for (int k0 = 0; k0 < K; k0 += 32) {
        __syncthreads();
#pragma unroll
        for (int hh = 0; hh < 2; hh++) {
            int r = hh * 64 + wave * 16 + lrow;
            gl_lds16(Ab + (size_t)(m0 + r) * K + k0 + lcol, &Alds[(hh * 64 + wave * 16) * 32]);
            gl_lds16(Bt + (size_t)(n0 + r) * K + k0 + lcol, &Blds[(hh * 64 + wave * 16) * 32]);
        }
        __syncthreads();
        bf16x8 af[4], bf[4];
#pragma unroll
        for (int i = 0; i < 4; i++) {
            af[i] = *(const bf16x8*)(&Alds[(wm0 + i * 16 + id15) * 32 + quad * 8]);
            bf[i] = *(const bf16x8*)(&Blds[(wn0 + i * 16 + id15) * 32 + quad * 8]);
        }
#pragma unroll
        for (int mi = 0; mi < 4; mi++)
#pragma unroll
            for (int ni = 0; ni < 4; ni++)
                acc[mi][ni] = __builtin_amdgcn_mfma_f32_16x16x32_bf16(
                    af[mi], bf[ni], acc[mi][ni], 0, 0, 0);
    }

#pragma unroll
    for (int ni = 0; ni < 4; ni++) {
        int n = n0 + wn0 + ni * 16 + id15;
        if (mode == 0) {
            int sect = n >> 10, nn = n & 1023, h = nn >> 6, d = nn & 63;
            float bvv = (sect == 0) ? b0[nn] : (sect == 1) ? b1[nn] : b2[nn];
#pragma unroll
            for (int mi = 0; mi < 4; mi++)
#pragma unroll
                for (int r = 0; r < 4; r++) {
                    int m = m0 + wm0 + mi * 16 + quad * 4 + r;
                    u16 w = f2bf(acc[mi][ni][r] + bvv);
                    if (sect == 0)
                        qb[(((size_t)b * Hh + h) * Tt + m) * Dd + d] = w;
                    else if (sect == 1)
                        kb[(((size_t)b * Hh + h) * Tt + m) * Dd + d] = w;
                    else
                        vT[(((size_t)b * Hh + h) * Dd + d) * Tt + m] = w;
                }
        } else {
            float bvv = b0[n];
#pragma unroll
            for (int mi = 0; mi < 4; mi++)
#pragma unroll
                for (int r = 0; r < 4; r++) {
                    int m = m0 + wm0 + mi * 16 + quad * 4 + r;
                    float mm = (float)mask[b * Tt + m];
                    out[((size_t)b * Cc + n) * Tt + m] = (acc[mi][ni][r] + bvv) * mm;
                }
        }
    }
}

// ---------------- attention: fixed-max softmax, key-split x2, no in-loop reductions ------
// Block: 4 waves. qg=wave&1 picks 16 queries (t0+qg*16), kh=wave>>1 picks key half.
// S^T = K*Q^T (query in lane column) -> p = exp(s/8)*maskf, per-lane l, P^T via shfl,
// O^T = V^T*P^T. Merge the two key halves via one LDS exchange at the end.
__global__ __launch_bounds__(256) void attn(const u16* __restrict__ q,
                                            const u16* __restrict__ kk,
                                            const u16* __restrict__ vT,
                                            const int* __restrict__ mask,
                                            u16* __restrict__ o_buf) {
    __shared__ float mbuf[2][64][17];
    int bh = blockIdx.y;
    int b = bh >> 4;
    int h = bh & 15;
    int t0 = blockIdx.x * 32;
    int tid = threadIdx.x;
    int lane = tid & 63, wave = tid >> 6;
    int quad = lane >> 4, id15 = lane & 15;
    int qg = wave & 1, kh = wave >> 1;
    int qrow = t0 + qg * 16;
    int koff = kh * (Tt / 2);
    const u16* qb = q + (size_t)bh * Tt * Dd;
    const u16* kb = kk + (size_t)bh * Tt * Dd;
    const u16* vb = vT + (size_t)bh * Dd * Tt;
    const int* mrow = mask + b * Tt;

    bf16x8 qf0 = *(const bf16x8*)(qb + (size_t)(qrow + id15) * Dd + quad * 8);
    bf16x8 qf1 = *(const bf16x8*)(qb + (size_t)(qrow + id15) * Dd + 32 + quad * 8);

    float l = 0.0f;
    f32x4 accO[4] = {};

    for (int j0 = koff; j0 < koff + Tt / 2; j0 += 32) {
        int4 mk0 = *(const int4*)(mrow + j0 + quad * 4);
        int4 mk1 = *(const int4*)(mrow + j0 + 16 + quad * 4);

        bf16x8 k00 = *(const bf16x8*)(kb + (size_t)(j0 + id15) * Dd + quad * 8);
        bf16x8 k01 = *(const bf16x8*)(kb + (size_t)(j0 + id15) * Dd + 32 + quad * 8);
        bf16x8 k10 = *(const bf16x8*)(kb + (size_t)(j0 + 16 + id15) * Dd + quad * 8);
        bf16x8 k11 = *(const bf16x8*)(kb + (size_t)(j0 + 16 + id15) * Dd + 32 + quad * 8);

        f32x4 st0 = {}, st1 = {};
        st0 = __builtin_amdgcn_mfma_f32_16x16x32_bf16(k00, qf0, st0, 0, 0, 0);
        st0 = __builtin_amdgcn_mfma_f32_16x16x32_bf16(k01, qf1, st0, 0, 0, 0);
        st1 = __builtin_amdgcn_mfma_f32_16x16x32_bf16(k10, qf0, st1, 0, 0, 0);
        st1 = __builtin_amdgcn_mfma_f32_16x16x32_bf16(k11, qf1, st1, 0, 0, 0);

        // fixed-max softmax numerator (scores bounded; exp cannot overflow fp32)
        float p00 = __expf(st0[0] * 0.125f) * (float)mk0.x;
        float p01 = __expf(st0[1] * 0.125f) * (float)mk0.y;
        float p02 = __expf(st0[2] * 0.125f) * (float)mk0.z;
        float p03 = __expf(st0[3] * 0.125f) * (float)mk0.w;
        float p10 = __expf(st1[0] * 0.125f) * (float)mk1.x;
        float p11 = __expf(st1[1] * 0.125f) * (float)mk1.y;
        float p12 = __expf(st1[2] * 0.125f) * (float)mk1.z;
        float p13 = __expf(st1[3] * 0.125f) * (float)mk1.w;
        l += ((p00 + p01) + (p02 + p03)) + ((p10 + p11) + (p12 + p13));

        u32 pk00 = pk_bf2(p00, p01), pk01 = pk_bf2(p02, p03);
        u32 pk10 = pk_bf2(p10, p11), pk11 = pk_bf2(p12, p13);

        // P^T B-fragment: slot s holds keys quad*8+2s,+2s+1 for query id15
        int s0 = ((quad & 1) * 2) * 16 + id15;
        int s1 = ((quad & 1) * 2 + 1) * 16 + id15;
        u32 a0 = (u32)__shfl((int)pk00, s0), a1 = (u32)__shfl((int)pk01, s0);
        u32 a2 = (u32)__shfl((int)pk00, s1), a3 = (u32)__shfl((int)pk01, s1);
        u32 c0 = (u32)__shfl((int)pk10, s0), c1 = (u32)__shfl((int)pk11, s0);
        u32 c2 = (u32)__shfl((int)pk10, s1), c3 = (u32)__shfl((int)pk11, s1);
        union { u32 u[4]; bf16x8 v; } pf;
        pf.u[0] = (quad < 2) ? a0 : c0;
        pf.u[1] = (quad < 2) ? a1 : c1;
        pf.u[2] = (quad < 2) ? a2 : c2;
        pf.u[3] = (quad < 2) ? a3 : c3;

#pragma unroll
        for (int mt = 0; mt < 4; mt++) {
            bf16x8 vf = *(const bf16x8*)(vb + (size_t)(mt * 16 + id15) * Tt + j0 + quad * 8);
            accO[mt] = __builtin_amdgcn_mfma_f32_16x16x32_bf16(vf, pf.v, accO[mt], 0, 0, 0);
        }
    }

    // per-query l: reduce across the 4 quads (lanes id15+16k share query id15)
    l += __shfl_xor(l, 16);
    l += __shfl_xor(l, 32);

    // merge the two key halves (unnormalized sums are additive under fixed max)
    if (kh == 1) {
#pragma unroll
        for (int mt = 0; mt < 4; mt++)
#pragma unroll
            for (int r = 0; r < 4; r++) mbuf[qg][lane][mt * 4 + r] = accO[mt][r];
        mbuf[qg][lane][16] = l;
    }
    __syncthreads();
    if (kh == 0) {
#pragma unroll
        for (int mt = 0; mt < 4; mt++)
#pragma unroll
            for (int r = 0; r < 4; r++) accO[mt][r] += mbuf[qg][lane][mt * 4 + r];
        l += mbuf[qg][lane][16];
        float inv = 1.0f / l;
#pragma unroll
        for (int mt = 0; mt < 4; mt++) {
            uint2 w;
            w.x = pk_bf2(accO[mt][0] * inv, accO[mt][1] * inv);
            w.y = pk_bf2(accO[mt][2] * inv, accO[mt][3] * inv);
            *(uint2*)(o_buf + ((size_t)b * Tt + qrow + id15) * Cc + h * Dd + mt * 16 +
                      quad * 4) = w;
        }
    }
}

// ---------------- mask tail of d_out (fp32 0/1) ----------------
__global__ void mask_out_k(const int* __restrict__ mask, float* __restrict__ out) {
    int i = blockIdx.x * 256 + threadIdx.x;
    if (i < Bb * Tt) out[i] = mask[i] ? 1.0f : 0.0f;
}

extern "C" void kernel_launch(void* const* d_in, const int* in_sizes, int n_in,
                              void* d_out, int out_size, void* d_ws, size_t ws_size,
                              hipStream_t stream) {
    const float* x  = (const float*)d_in[0];
    const int* mask = (const int*)d_in[1];
    const float* Wq = (const float*)d_in[2];
    const float* bq = (const float*)d_in[3];
    const float* Wk = (const float*)d_in[4];
    const float* bk = (const float*)d_in[5];
    const float* Wv = (const float*)d_in[6];
    const float* bv = (const float*)d_in[7];
    const float* Wp = (const float*)d_in[8];
    const float* bp = (const float*)d_in[9];
    float* out = (float*)d_out;

    size_t sz = (size_t)Bb * Tt * Cc;
    size_t wsz = (size_t)Cc * Cc;
    u16* xT = (u16*)d_ws;
    u16* qb = xT + sz;
    u16* kb = qb + sz;
    u16* vT = kb + sz;
    u16* wq16 = vT + sz;   // wq16/wk16/wv16 contiguous => fused [3072][1024] B matrix
    u16* wk16 = wq16 + wsz;
    u16* wv16 = wk16 + wsz;
    u16* wp16 = wv16 + wsz;
    u16* ob = xT;  // reuse xT: last read by QKV gemm, attn writes after (stream-ordered)

    int cvb = (int)(wsz / 4 / 256);
    cvt_bf16<<<cvb, 256, 0, stream>>>(Wq, wq16, (int)wsz);
    cvt_bf16<<<cvb, 256, 0, stream>>>(Wk, wk16, (int)wsz);
    cvt_bf16<<<cvb, 256, 0, stream>>>(Wv, wv16, (int)wsz);
    cvt_bf16<<<cvb, 256, 0, stream>>>(Wp, wp16, (int)wsz);
    transpose_x<<<dim3(Tt / 32, Cc / 32, Bb), dim3(32, 8), 0, stream>>>(x, xT);
    // fused QKV: N=3072
    gemm128<<<dim3(3 * Cc / 128, Tt / 128, Bb), 256, 0, stream>>>(
        xT, wq16, bq, bk, bv, nullptr, qb, kb, vT, nullptr, 0);
    attn<<<dim3(Tt / 32, Bb * Hh), 256, 0, stream>>>(qb, kb, vT, mask, ob);
    gemm128<<<dim3(Cc / 128, Tt / 128, Bb), 256, 0, stream>>>(
        ob, wp16, bp, bp, bp, mask, nullptr, nullptr, nullptr, out, 1);
    if (out_size >= Bb * Cc * Tt + Bb * Tt)
        mask_out_k<<<dim3((Bb * Tt + 255) / 256), 256, 0, stream>>>(
            mask, out + (size_t)Bb * Cc * Tt);
}

// Round 5
// 279.780 us; speedup vs baseline: 1.6051x; 1.5371x over previous
//
#include <hip/hip_runtime.h>

typedef unsigned short u16;
typedef unsigned int u32;
typedef short bf16x8 __attribute__((ext_vector_type(8)));
typedef float f32x4 __attribute__((ext_vector_type(4)));

constexpr int Bb = 2, Cc = 1024, Tt = 2048, Hh = 16, Dd = 64;

__device__ __forceinline__ u16 f2bf(float f) {
    union { float f; u32 i; } c; c.f = f;
    u32 u = c.i;
    u32 r = (u + 0x7FFFu + ((u >> 16) & 1u)) >> 16;
    return (u16)r;
}
// pack two fp32 -> bf16x2 (round-half-up)
__device__ __forceinline__ u32 pk_bf2(float lo, float hi) {
    union { float f; u32 i; } a, b; a.f = lo; b.f = hi;
    u32 ua = a.i + 0x8000u, ub = b.i + 0x8000u;
    return (ub & 0xFFFF0000u) | (ua >> 16);
}
// async global->LDS, 16B/lane; lds base wave-uniform, lane L lands at base+16L
__device__ __forceinline__ void gl_lds16(const u16* g, u16* l) {
    __builtin_amdgcn_global_load_lds(
        (const __attribute__((address_space(1))) u32*)(const void*)g,
        (__attribute__((address_space(3))) u32*)(void*)l, 16, 0, 0);
}

// ---------------- fp32 -> bf16 elementwise (weights) ----------------
__global__ __launch_bounds__(256) void cvt_bf16(const float* __restrict__ in,
                                                u16* __restrict__ out, int n) {
    int i = (blockIdx.x * 256 + threadIdx.x) * 4;
    if (i + 3 < n) {
        float4 v = *(const float4*)(in + i);
        out[i + 0] = f2bf(v.x);
        out[i + 1] = f2bf(v.y);
        out[i + 2] = f2bf(v.z);
        out[i + 3] = f2bf(v.w);
    }
}

// ---------------- x transpose+convert: fp32 [b][c][t] -> bf16 [b][t][c] ----------------
__global__ __launch_bounds__(256) void transpose_x(const float* __restrict__ x,
                                                   u16* __restrict__ xT) {
    __shared__ u16 tile[32][33];
    int b = blockIdx.z;
    int t0 = blockIdx.x * 32, c0 = blockIdx.y * 32;
    int tx = threadIdx.x, ty = threadIdx.y;
    const float* xb = x + (size_t)b * Cc * Tt;
    u16* xTb = xT + (size_t)b * Tt * Cc;
#pragma unroll
    for (int i = 0; i < 4; i++) {
        int r = ty + i * 8;
        tile[r][tx] = f2bf(xb[(size_t)(c0 + r) * Tt + t0 + tx]);
    }
    __syncthreads();
#pragma unroll
    for (int i = 0; i < 4; i++) {
        int r = ty + i * 8;
        xTb[(size_t)(t0 + r) * Cc + c0 + tx] = tile[tx][r];
    }
}

// ---------------- 128x128x32 GEMM, global_load_lds staging (m97 structure) ----------------
// mode 0: N=3072 fused QKV -> qb/kb (b,h,t,d) and vT (b,h,d,t), bias by section
// mode 1: N=1024 proj -> out fp32 [b][n][t] = (acc+b0[n]) * mask[b][t]
__global__ __launch_bounds__(256) void gemm128(const u16* __restrict__ A,
                                               const u16* __restrict__ Bt,
                                               const float* __restrict__ b0,
                                               const float* __restrict__ b1,
                                               const float* __restrict__ b2,
                                               const int* __restrict__ mask,
                                               u16* __restrict__ qb, u16* __restrict__ kb,
                                               u16* __restrict__ vT, float* __restrict__ out,
                                               int mode) {
    constexpr int K = Cc;
    __shared__ u16 Alds[128 * 32];
    __shared__ u16 Blds[128 * 32];
    int b = blockIdx.z;
    int n0 = blockIdx.x * 128, m0 = blockIdx.y * 128;
    int tid = threadIdx.x;
    int lane = tid & 63, wave = tid >> 6;
    int quad = lane >> 4, id15 = lane & 15;
    int wm0 = (wave & 1) * 64, wn0 = (wave >> 1) * 64;
    const u16* Ab = A + (size_t)b * Tt * K;
    int lrow = lane >> 2, lcol = (lane & 3) * 8;

    f32x4 acc[4][4] = {};

    for (int k0 = 0; k0 < K; k0 += 32) {
        __syncthreads();
#pragma unroll
        for (int hh = 0; hh < 2; hh++) {
            int r = hh * 64 + wave * 16 + lrow;
            gl_lds16(Ab + (size_t)(m0 + r) * K + k0 + lcol, &Alds[(hh * 64 + wave * 16) * 32]);
            gl_lds16(Bt + (size_t)(n0 + r) * K + k0 + lcol, &Blds[(hh * 64 + wave * 16) * 32]);
        }
        __syncthreads();
        bf16x8 af[4], bf[4];
#pragma unroll
        for (int i = 0; i < 4; i++) {
            af[i] = *(const bf16x8*)(&Alds[(wm0 + i * 16 + id15) * 32 + quad * 8]);
            bf[i] = *(const bf16x8*)(&Blds[(wn0 + i * 16 + id15) * 32 + quad * 8]);
        }
#pragma unroll
        for (int mi = 0; mi < 4; mi++)
#pragma unroll
            for (int ni = 0; ni < 4; ni++)
                acc[mi][ni] = __builtin_amdgcn_mfma_f32_16x16x32_bf16(
                    af[mi], bf[ni], acc[mi][ni], 0, 0, 0);
    }

#pragma unroll
    for (int ni = 0; ni < 4; ni++) {
        int n = n0 + wn0 + ni * 16 + id15;
        if (mode == 0) {
            int sect = n >> 10, nn = n & 1023, h = nn >> 6, d = nn & 63;
            float bvv = (sect == 0) ? b0[nn] : (sect == 1) ? b1[nn] : b2[nn];
#pragma unroll
            for (int mi = 0; mi < 4; mi++)
#pragma unroll
                for (int r = 0; r < 4; r++) {
                    int m = m0 + wm0 + mi * 16 + quad * 4 + r;
                    u16 w = f2bf(acc[mi][ni][r] + bvv);
                    if (sect == 0)
                        qb[(((size_t)b * Hh + h) * Tt + m) * Dd + d] = w;
                    else if (sect == 1)
                        kb[(((size_t)b * Hh + h) * Tt + m) * Dd + d] = w;
                    else
                        vT[(((size_t)b * Hh + h) * Dd + d) * Tt + m] = w;
                }
        } else {
            float bvv = b0[n];
#pragma unroll
            for (int mi = 0; mi < 4; mi++) {
                int m = m0 + wm0 + mi * 16 + quad * 4;
                int4 m4 = *(const int4*)(&mask[b * Tt + m]);
                float4 w;
                w.x = (acc[mi][ni][0] + bvv) * (float)m4.x;
                w.y = (acc[mi][ni][1] + bvv) * (float)m4.y;
                w.z = (acc[mi][ni][2] + bvv) * (float)m4.z;
                w.w = (acc[mi][ni][3] + bvv) * (float)m4.w;
                *(float4*)(&out[((size_t)b * Cc + n) * Tt + m]) = w;
            }
        }
    }
}

// ---------------- staged flash attention: Q-tile 128, 64-key LDS chunks ----------------
// q,k: [b][h][t][d] bf16 ; vT: [b][h][d][t] bf16 ; o_buf: [b][t][h*64+d] bf16
// Each wave owns 32 queries (2 groups of 16). K/V chunks double-buffered in LDS
// via global_load_lds; 16B chunks XOR-swizzled (phys = logical ^ (row&7)) so
// ds_read_b128 fragment reads are <=2-way bank aliased (free). Fixed-max softmax.
__global__ __launch_bounds__(256) void attn(const u16* __restrict__ q,
                                            const u16* __restrict__ kk,
                                            const u16* __restrict__ vT,
                                            const int* __restrict__ mask,
                                            u16* __restrict__ o_buf) {
    __shared__ u16 Kl[2][64 * 64];  // [buf][key-row*64 + swizzled d]
    __shared__ u16 Vl[2][64 * 64];  // [buf][d-row*64  + swizzled key]
    int bh = blockIdx.y;
    int b = bh >> 4, h = bh & 15;
    int t0 = blockIdx.x * 128;
    int tid = threadIdx.x;
    int lane = tid & 63, wave = tid >> 6;
    int quad = lane >> 4, id15 = lane & 15;
    int wq = t0 + wave * 32;
    const u16* qb = q + (size_t)bh * Tt * Dd;
    const u16* kb = kk + (size_t)bh * Tt * Dd;
    const u16* vb = vT + (size_t)bh * Dd * Tt;
    const int* mrow = mask + b * Tt;

    // Q fragments (B-operand): query col = qg*16+id15, d = hf*32+quad*8..
    bf16x8 qf[2][2];
#pragma unroll
    for (int qg = 0; qg < 2; qg++)
#pragma unroll
        for (int hf = 0; hf < 2; hf++)
            qf[qg][hf] = *(const bf16x8*)(qb + (size_t)(wq + qg * 16 + id15) * Dd +
                                          hf * 32 + quad * 8);

    // staging geometry: 512 16B-slots each for K and V; this wave covers
    // slots wave*128 .. +127 with two instructions. slot g -> row g>>3,
    // chunk g&7, fetching global chunk (g&7)^(row&7).
    int sg0 = wave * 128 + lane;
    int sg1 = sg0 + 64;
    int r0 = sg0 >> 3, sw0 = ((sg0 & 7) ^ (r0 & 7)) * 8;
    int r1 = sg1 >> 3, sw1 = ((sg1 & 7) ^ (r1 & 7)) * 8;

    float l[2] = {0.0f, 0.0f};
    f32x4 accO[4][2] = {};

    // prologue stage chunk 0 into buf 0
    {
        gl_lds16(kb + (size_t)r0 * Dd + sw0, &Kl[0][(wave * 128) * 8]);
        gl_lds16(kb + (size_t)r1 * Dd + sw1, &Kl[0][(wave * 128 + 64) * 8]);
        gl_lds16(vb + (size_t)r0 * Tt + sw0, &Vl[0][(wave * 128) * 8]);
        gl_lds16(vb + (size_t)r1 * Tt + sw1, &Vl[0][(wave * 128 + 64) * 8]);
    }

    int shA = ((quad & 1) * 2) * 16 + id15;  // src lane for pf slots 0,1
    int shB = shA + 16;                      // src lane for pf slots 2,3

    for (int c = 0; c < 32; c++) {
        int j0 = c * 64;
        __syncthreads();  // staged buf (c&1) visible; prev compute done
        if (c < 31) {
            int bb = (c + 1) & 1, jn = j0 + 64;
            gl_lds16(kb + (size_t)(jn + r0) * Dd + sw0, &Kl[bb][(wave * 128) * 8]);
            gl_lds16(kb + (size_t)(jn + r1) * Dd + sw1, &Kl[bb][(wave * 128 + 64) * 8]);
            gl_lds16(vb + (size_t)r0 * Tt + jn + sw0, &Vl[bb][(wave * 128) * 8]);
            gl_lds16(vb + (size_t)r1 * Tt + jn + sw1, &Vl[bb][(wave * 128 + 64) * 8]);
        }
        const u16* Kb = Kl[c & 1];
        const u16* Vb = Vl[c & 1];

        // S^T[key][query] for 64 keys x 32 queries
        f32x4 st[4][2] = {};
#pragma unroll
        for (int kt = 0; kt < 4; kt++) {
            int krow = kt * 16 + id15;
            int swz = krow & 7;
#pragma unroll
            for (int hf = 0; hf < 2; hf++) {
                bf16x8 kf = *(const bf16x8*)(Kb + krow * 64 + (((hf << 2) | quad) ^ swz) * 8);
                st[kt][0] = __builtin_amdgcn_mfma_f32_16x16x32_bf16(kf, qf[0][hf], st[kt][0], 0, 0, 0);
                st[kt][1] = __builtin_amdgcn_mfma_f32_16x16x32_bf16(kf, qf[1][hf], st[kt][1], 0, 0, 0);
            }
        }

        // fixed-max softmax numerator + bf16 pack
        u32 pk[2][2][2][2];
#pragma unroll
        for (int kt = 0; kt < 4; kt++) {
            int4 mk = *(const int4*)(mrow + j0 + kt * 16 + quad * 4);
            float f0 = (float)mk.x, f1 = (float)mk.y, f2 = (float)mk.z, f3 = (float)mk.w;
#pragma unroll
            for (int qg = 0; qg < 2; qg++) {
                float p0 = __expf(st[kt][qg][0] * 0.125f) * f0;
                float p1 = __expf(st[kt][qg][1] * 0.125f) * f1;
                float p2 = __expf(st[kt][qg][2] * 0.125f) * f2;
                float p3 = __expf(st[kt][qg][3] * 0.125f) * f3;
                l[qg] += (p0 + p1) + (p2 + p3);
                pk[kt >> 1][qg][kt & 1][0] = pk_bf2(p0, p1);
                pk[kt >> 1][qg][kt & 1][1] = pk_bf2(p2, p3);
            }
        }

        // per 32-key group: build P^T B-frag via shfl, then PV MFMAs
#pragma unroll
        for (int g = 0; g < 2; g++) {
            union { u32 u[4]; bf16x8 v; } pf[2];
#pragma unroll
            for (int qg = 0; qg < 2; qg++) {
                u32 a0 = (u32)__shfl((int)pk[g][qg][0][0], shA);
                u32 a1 = (u32)__shfl((int)pk[g][qg][0][1], shA);
                u32 a2 = (u32)__shfl((int)pk[g][qg][0][0], shB);
                u32 a3 = (u32)__shfl((int)pk[g][qg][0][1], shB);
                u32 c0 = (u32)__shfl((int)pk[g][qg][1][0], shA);
                u32 c1 = (u32)__shfl((int)pk[g][qg][1][1], shA);
                u32 c2 = (u32)__shfl((int)pk[g][qg][1][0], shB);
                u32 c3 = (u32)__shfl((int)pk[g][qg][1][1], shB);
                pf[qg].u[0] = (quad < 2) ? a0 : c0;
                pf[qg].u[1] = (quad < 2) ? a1 : c1;
                pf[qg].u[2] = (quad < 2) ? a2 : c2;
                pf[qg].u[3] = (quad < 2) ? a3 : c3;
            }
#pragma unroll
            for (int dt = 0; dt < 4; dt++) {
                int drow = dt * 16 + id15;
                bf16x8 vf = *(const bf16x8*)(Vb + drow * 64 +
                                             (((g << 2) | quad) ^ (drow & 7)) * 8);
                accO[dt][0] = __builtin_amdgcn_mfma_f32_16x16x32_bf16(vf, pf[0].v, accO[dt][0], 0, 0, 0);
                accO[dt][1] = __builtin_amdgcn_mfma_f32_16x16x32_bf16(vf, pf[1].v, accO[dt][1], 0, 0, 0);
            }
        }
    }

    // normalize + write O^T fragments: row d = dt*16+quad*4+r, col q = qg*16+id15
#pragma unroll
    for (int qg = 0; qg < 2; qg++) {
        float lv = l[qg];
        lv += __shfl_xor(lv, 16);
        lv += __shfl_xor(lv, 32);
        float inv = 1.0f / lv;
#pragma unroll
        for (int dt = 0; dt < 4; dt++) {
            uint2 w;
            w.x = pk_bf2(accO[dt][qg][0] * inv, accO[dt][qg][1] * inv);
            w.y = pk_bf2(accO[dt][qg][2] * inv, accO[dt][qg][3] * inv);
            *(uint2*)(o_buf + ((size_t)b * Tt + wq + qg * 16 + id15) * Cc + h * Dd +
                      dt * 16 + quad * 4) = w;
        }
    }
}

// ---------------- mask tail of d_out (fp32 0/1) ----------------
__global__ void mask_out_k(const int* __restrict__ mask, float* __restrict__ out) {
    int i = blockIdx.x * 256 + threadIdx.x;
    if (i < Bb * Tt) out[i] = mask[i] ? 1.0f : 0.0f;
}

extern "C" void kernel_launch(void* const* d_in, const int* in_sizes, int n_in,
                              void* d_out, int out_size, void* d_ws, size_t ws_size,
                              hipStream_t stream) {
    const float* x  = (const float*)d_in[0];
    const int* mask = (const int*)d_in[1];
    const float* Wq = (const float*)d_in[2];
    const float* bq = (const float*)d_in[3];
    const float* Wk = (const float*)d_in[4];
    const float* bk = (const float*)d_in[5];
    const float* Wv = (const float*)d_in[6];
    const float* bv = (const float*)d_in[7];
    const float* Wp = (const float*)d_in[8];
    const float* bp = (const float*)d_in[9];
    float* out = (float*)d_out;

    size_t sz = (size_t)Bb * Tt * Cc;
    size_t wsz = (size_t)Cc * Cc;
    u16* xT = (u16*)d_ws;
    u16* qb = xT + sz;
    u16* kb = qb + sz;
    u16* vT = kb + sz;
    u16* wq16 = vT + sz;   // wq16/wk16/wv16 contiguous => fused [3072][1024] B matrix
    u16* wk16 = wq16 + wsz;
    u16* wv16 = wk16 + wsz;
    u16* wp16 = wv16 + wsz;
    u16* ob = xT;  // reuse xT: last read by QKV gemm, attn writes after (stream-ordered)

    int cvb = (int)(wsz / 4 / 256);
    cvt_bf16<<<cvb, 256, 0, stream>>>(Wq, wq16, (int)wsz);
    cvt_bf16<<<cvb, 256, 0, stream>>>(Wk, wk16, (int)wsz);
    cvt_bf16<<<cvb, 256, 0, stream>>>(Wv, wv16, (int)wsz);
    cvt_bf16<<<cvb, 256, 0, stream>>>(Wp, wp16, (int)wsz);
    transpose_x<<<dim3(Tt / 32, Cc / 32, Bb), dim3(32, 8), 0, stream>>>(x, xT);
    gemm128<<<dim3(3 * Cc / 128, Tt / 128, Bb), 256, 0, stream>>>(
        xT, wq16, bq, bk, bv, nullptr, qb, kb, vT, nullptr, 0);
    attn<<<dim3(Tt / 128, Bb * Hh), 256, 0, stream>>>(qb, kb, vT, mask, ob);
    gemm128<<<dim3(Cc / 128, Tt / 128, Bb), 256, 0, stream>>>(
        ob, wp16, bp, bp, bp, mask, nullptr, nullptr, nullptr, out, 1);
    if (out_size >= Bb * Cc * Tt + Bb * Tt)
        mask_out_k<<<dim3((Bb * Tt + 255) / 256), 256, 0, stream>>>(
            mask, out + (size_t)Bb * Cc * Tt);
}

// Round 6
// 258.043 us; speedup vs baseline: 1.7403x; 1.0842x over previous
//
#include <hip/hip_runtime.h>

typedef unsigned short u16;
typedef unsigned int u32;
typedef short bf16x8 __attribute__((ext_vector_type(8)));
typedef float f32x4 __attribute__((ext_vector_type(4)));

constexpr int Bb = 2, Cc = 1024, Tt = 2048, Hh = 16, Dd = 64;

__device__ __forceinline__ u16 f2bf(float f) {
    union { float f; u32 i; } c; c.f = f;
    u32 u = c.i;
    u32 r = (u + 0x7FFFu + ((u >> 16) & 1u)) >> 16;
    return (u16)r;
}
// pack two fp32 -> bf16x2 (round-half-up)
__device__ __forceinline__ u32 pk_bf2(float lo, float hi) {
    union { float f; u32 i; } a, b; a.f = lo; b.f = hi;
    u32 ua = a.i + 0x8000u, ub = b.i + 0x8000u;
    return (ub & 0xFFFF0000u) | (ua >> 16);
}
// async global->LDS, 16B/lane; lds base wave-uniform, lane L lands at base+16L
__device__ __forceinline__ void gl_lds16(const u16* g, u16* l) {
    __builtin_amdgcn_global_load_lds(
        (const __attribute__((address_space(1))) u32*)(const void*)g,
        (__attribute__((address_space(3))) u32*)(void*)l, 16, 0, 0);
}

// ---------------- fp32 -> bf16 elementwise (weights) ----------------
__global__ __launch_bounds__(256) void cvt_bf16(const float* __restrict__ in,
                                                u16* __restrict__ out, int n) {
    int i = (blockIdx.x * 256 + threadIdx.x) * 4;
    if (i + 3 < n) {
        float4 v = *(const float4*)(in + i);
        out[i + 0] = f2bf(v.x);
        out[i + 1] = f2bf(v.y);
        out[i + 2] = f2bf(v.z);
        out[i + 3] = f2bf(v.w);
    }
}

// ---------------- x transpose+convert: fp32 [b][c][t] -> bf16 [b][t][c] ----------------
__global__ __launch_bounds__(256) void transpose_x(const float* __restrict__ x,
                                                   u16* __restrict__ xT) {
    __shared__ u16 tile[32][33];
    int b = blockIdx.z;
    int t0 = blockIdx.x * 32, c0 = blockIdx.y * 32;
    int tx = threadIdx.x, ty = threadIdx.y;
    const float* xb = x + (size_t)b * Cc * Tt;
    u16* xTb = xT + (size_t)b * Tt * Cc;
#pragma unroll
    for (int i = 0; i < 4; i++) {
        int r = ty + i * 8;
        tile[r][tx] = f2bf(xb[(size_t)(c0 + r) * Tt + t0 + tx]);
    }
    __syncthreads();
#pragma unroll
    for (int i = 0; i < 4; i++) {
        int r = ty + i * 8;
        xTb[(size_t)(t0 + r) * Cc + c0 + tx] = tile[tx][r];
    }
}

// ============ fused QKV GEMM: A[4096][1024] x W[3072][1024]^T, 128x128 tiles ============
// LDS rows = 32 u16 (64 B); 16B chunks XOR-swizzled: phys = chunk ^ ((row>>1)&3)
// -> ds_read_b128 fragment reads are 2-way bank-aliased (free, m136).
// MFMA operand order (bf, af): C rows = n (4 consecutive channels per lane) ->
// vectorized q/k uint2 stores, lane-coalesced vT stores.
__global__ __launch_bounds__(256) void gemm_qkv(const u16* __restrict__ A,
                                                const u16* __restrict__ Bt,
                                                const float* __restrict__ b0,
                                                const float* __restrict__ b1,
                                                const float* __restrict__ b2,
                                                u16* __restrict__ qb, u16* __restrict__ kb,
                                                u16* __restrict__ vT) {
    constexpr int K = Cc;
    __shared__ u16 Alds[128 * 32];
    __shared__ u16 Blds[128 * 32];
    int n0 = blockIdx.x * 128, m0 = blockIdx.y * 128;
    int tid = threadIdx.x;
    int lane = tid & 63, wave = tid >> 6;
    int quad = lane >> 4, id15 = lane & 15;
    int wm0 = (wave & 1) * 64, wn0 = (wave >> 1) * 64;
    int srow = lane >> 2;
    int scol = ((lane & 3) ^ ((lane >> 3) & 3)) * 8;  // swizzled source chunk (elems)
    int sw = (id15 >> 1) & 3;                         // read-side swizzle

    f32x4 acc[4][4] = {};  // [ni][mi]

    for (int k0 = 0; k0 < K; k0 += 32) {
        __syncthreads();
#pragma unroll
        for (int hh = 0; hh < 2; hh++) {
            int rb = hh * 64 + wave * 16;
            gl_lds16(A + (size_t)(m0 + rb + srow) * K + k0 + scol, &Alds[rb * 32]);
            gl_lds16(Bt + (size_t)(n0 + rb + srow) * K + k0 + scol, &Blds[rb * 32]);
        }
        __syncthreads();
        bf16x8 af[4], bf[4];
#pragma unroll
        for (int i = 0; i < 4; i++) {
            af[i] = *(const bf16x8*)(&Alds[(wm0 + i * 16 + id15) * 32 + (quad ^ sw) * 8]);
            bf[i] = *(const bf16x8*)(&Blds[(wn0 + i * 16 + id15) * 32 + (quad ^ sw) * 8]);
        }
#pragma unroll
        for (int ni = 0; ni < 4; ni++)
#pragma unroll
            for (int mi = 0; mi < 4; mi++)
                acc[ni][mi] = __builtin_amdgcn_mfma_f32_16x16x32_bf16(
                    bf[ni], af[mi], acc[ni][mi], 0, 0, 0);
    }

    int bb = m0 >> 11;        // batch (block-uniform; 2048 rows per batch)
    int mt0 = (m0 & 2047) + wm0;
#pragma unroll
    for (int ni = 0; ni < 4; ni++) {
        int nr = n0 + wn0 + ni * 16 + quad * 4;  // 4 consecutive output channels
        int sect = nr >> 10;                     // block-uniform
        int nn = nr & 1023;
        int h = nn >> 6, d0 = nn & 63;
        const float* bp_ = (sect == 0) ? b0 : (sect == 1) ? b1 : b2;
        float4 bv4 = *(const float4*)(bp_ + nn);
        if (sect < 2) {
            u16* dst = ((sect == 0) ? qb : kb) + ((size_t)bb * Hh + h) * Tt * (size_t)Dd;
#pragma unroll
            for (int mi = 0; mi < 4; mi++) {
                int mt = mt0 + mi * 16 + id15;
                uint2 w;
                w.x = pk_bf2(acc[ni][mi][0] + bv4.x, acc[ni][mi][1] + bv4.y);
                w.y = pk_bf2(acc[ni][mi][2] + bv4.z, acc[ni][mi][3] + bv4.w);
                *(uint2*)(dst + (size_t)mt * Dd + d0) = w;
            }
        } else {
            u16* dst = vT + ((size_t)bb * Hh + h) * Dd * (size_t)Tt;
#pragma unroll
            for (int mi = 0; mi < 4; mi++) {
                int mt = mt0 + mi * 16 + id15;
                dst[(size_t)(d0 + 0) * Tt + mt] = f2bf(acc[ni][mi][0] + bv4.x);
                dst[(size_t)(d0 + 1) * Tt + mt] = f2bf(acc[ni][mi][1] + bv4.y);
                dst[(size_t)(d0 + 2) * Tt + mt] = f2bf(acc[ni][mi][2] + bv4.z);
                dst[(size_t)(d0 + 3) * Tt + mt] = f2bf(acc[ni][mi][3] + bv4.w);
            }
        }
    }
}

// ============ proj GEMM: A[4096][1024] x Wp[1024][1024]^T, 64n x 128m tiles ============
// out fp32 [b][n][t] = (acc + bias[n]) * mask[b][t]
__global__ __launch_bounds__(256) void gemm_proj(const u16* __restrict__ A,
                                                 const u16* __restrict__ Bt,
                                                 const float* __restrict__ b0,
                                                 const int* __restrict__ mask,
                                                 float* __restrict__ out) {
    constexpr int K = Cc;
    __shared__ u16 Alds[128 * 32];
    __shared__ u16 Blds[64 * 32];
    int n0 = blockIdx.x * 64, m0 = blockIdx.y * 128;
    int tid = threadIdx.x;
    int lane = tid & 63, wave = tid >> 6;
    int quad = lane >> 4, id15 = lane & 15;
    int wn0 = (wave & 1) * 32, wm0 = (wave >> 1) * 64;
    int srow = lane >> 2;
    int scol = ((lane & 3) ^ ((lane >> 3) & 3)) * 8;
    int sw = (id15 >> 1) & 3;

    f32x4 acc[2][4] = {};  // [ni][mi]

    for (int k0 = 0; k0 < K; k0 += 32) {
        __syncthreads();
#pragma unroll
        for (int hh = 0; hh < 2; hh++) {
            int rb = hh * 64 + wave * 16;
            gl_lds16(A + (size_t)(m0 + rb + srow) * K + k0 + scol, &Alds[rb * 32]);
        }
        {
            int rb = wave * 16;
            gl_lds16(Bt + (size_t)(n0 + rb + srow) * K + k0 + scol, &Blds[rb * 32]);
        }
        __syncthreads();
        bf16x8 af[4], bf[2];
#pragma unroll
        for (int i = 0; i < 4; i++)
            af[i] = *(const bf16x8*)(&Alds[(wm0 + i * 16 + id15) * 32 + (quad ^ sw) * 8]);
#pragma unroll
        for (int i = 0; i < 2; i++)
            bf[i] = *(const bf16x8*)(&Blds[(wn0 + i * 16 + id15) * 32 + (quad ^ sw) * 8]);
#pragma unroll
        for (int ni = 0; ni < 2; ni++)
#pragma unroll
            for (int mi = 0; mi < 4; mi++)
                acc[ni][mi] = __builtin_amdgcn_mfma_f32_16x16x32_bf16(
                    bf[ni], af[mi], acc[ni][mi], 0, 0, 0);
    }

    int bb = m0 >> 11;
    int mt0 = (m0 & 2047) + wm0;
#pragma unroll
    for (int ni = 0; ni < 2; ni++) {
        int nr = n0 + wn0 + ni * 16 + quad * 4;
        float4 bv4 = *(const float4*)(b0 + nr);
#pragma unroll
        for (int mi = 0; mi < 4; mi++) {
            int m = mt0 + mi * 16 + id15;            // t within batch
            int mg = (bb << 11) + m;                 // global row (mask is [b][t] flat)
            float mm = (float)mask[mg];
            float* o = out + ((size_t)bb * Cc + nr) * Tt + m;
            o[0 * Tt] = (acc[ni][mi][0] + bv4.x) * mm;
            o[1 * Tt] = (acc[ni][mi][1] + bv4.y) * mm;
            o[2 * Tt] = (acc[ni][mi][2] + bv4.z) * mm;
            o[3 * Tt] = (acc[ni][mi][3] + bv4.w) * mm;
        }
    }
}

// ---------------- staged flash attention: Q-tile 128, 64-key LDS chunks ----------------
// (unchanged from round 5)
__global__ __launch_bounds__(256) void attn(const u16* __restrict__ q,
                                            const u16* __restrict__ kk,
                                            const u16* __restrict__ vT,
                                            const int* __restrict__ mask,
                                            u16* __restrict__ o_buf) {
    __shared__ u16 Kl[2][64 * 64];
    __shared__ u16 Vl[2][64 * 64];
    int bh = blockIdx.y;
    int b = bh >> 4, h = bh & 15;
    int t0 = blockIdx.x * 128;
    int tid = threadIdx.x;
    int lane = tid & 63, wave = tid >> 6;
    int quad = lane >> 4, id15 = lane & 15;
    int wq = t0 + wave * 32;
    const u16* qb = q + (size_t)bh * Tt * Dd;
    const u16* kb = kk + (size_t)bh * Tt * Dd;
    const u16* vb = vT + (size_t)bh * Dd * Tt;
    const int* mrow = mask + b * Tt;

    bf16x8 qf[2][2];
#pragma unroll
    for (int qg = 0; qg < 2; qg++)
#pragma unroll
        for (int hf = 0; hf < 2; hf++)
            qf[qg][hf] = *(const bf16x8*)(qb + (size_t)(wq + qg * 16 + id15) * Dd +
                                          hf * 32 + quad * 8);

    int sg0 = wave * 128 + lane;
    int sg1 = sg0 + 64;
    int r0 = sg0 >> 3, sw0 = ((sg0 & 7) ^ (r0 & 7)) * 8;
    int r1 = sg1 >> 3, sw1 = ((sg1 & 7) ^ (r1 & 7)) * 8;

    float l[2] = {0.0f, 0.0f};
    f32x4 accO[4][2] = {};

    {
        gl_lds16(kb + (size_t)r0 * Dd + sw0, &Kl[0][(wave * 128) * 8]);
        gl_lds16(kb + (size_t)r1 * Dd + sw1, &Kl[0][(wave * 128 + 64) * 8]);
        gl_lds16(vb + (size_t)r0 * Tt + sw0, &Vl[0][(wave * 128) * 8]);
        gl_lds16(vb + (size_t)r1 * Tt + sw1, &Vl[0][(wave * 128 + 64) * 8]);
    }

    int shA = ((quad & 1) * 2) * 16 + id15;
    int shB = shA + 16;

    for (int c = 0; c < 32; c++) {
        int j0 = c * 64;
        __syncthreads();
        if (c < 31) {
            int bb = (c + 1) & 1, jn = j0 + 64;
            gl_lds16(kb + (size_t)(jn + r0) * Dd + sw0, &Kl[bb][(wave * 128) * 8]);
            gl_lds16(kb + (size_t)(jn + r1) * Dd + sw1, &Kl[bb][(wave * 128 + 64) * 8]);
            gl_lds16(vb + (size_t)r0 * Tt + jn + sw0, &Vl[bb][(wave * 128) * 8]);
            gl_lds16(vb + (size_t)r1 * Tt + jn + sw1, &Vl[bb][(wave * 128 + 64) * 8]);
        }
        const u16* Kb = Kl[c & 1];
        const u16* Vb = Vl[c & 1];

        f32x4 st[4][2] = {};
#pragma unroll
        for (int kt = 0; kt < 4; kt++) {
            int krow = kt * 16 + id15;
            int swz = krow & 7;
#pragma unroll
            for (int hf = 0; hf < 2; hf++) {
                bf16x8 kf = *(const bf16x8*)(Kb + krow * 64 + (((hf << 2) | quad) ^ swz) * 8);
                st[kt][0] = __builtin_amdgcn_mfma_f32_16x16x32_bf16(kf, qf[0][hf], st[kt][0], 0, 0, 0);
                st[kt][1] = __builtin_amdgcn_mfma_f32_16x16x32_bf16(kf, qf[1][hf], st[kt][1], 0, 0, 0);
            }
        }

        u32 pk[2][2][2][2];
#pragma unroll
        for (int kt = 0; kt < 4; kt++) {
            int4 mk = *(const int4*)(mrow + j0 + kt * 16 + quad * 4);
            float f0 = (float)mk.x, f1 = (float)mk.y, f2 = (float)mk.z, f3 = (float)mk.w;
#pragma unroll
            for (int qg = 0; qg < 2; qg++) {
                float p0 = __expf(st[kt][qg][0] * 0.125f) * f0;
                float p1 = __expf(st[kt][qg][1] * 0.125f) * f1;
                float p2 = __expf(st[kt][qg][2] * 0.125f) * f2;
                float p3 = __expf(st[kt][qg][3] * 0.125f) * f3;
                l[qg] += (p0 + p1) + (p2 + p3);
                pk[kt >> 1][qg][kt & 1][0] = pk_bf2(p0, p1);
                pk[kt >> 1][qg][kt & 1][1] = pk_bf2(p2, p3);
            }
        }

#pragma unroll
        for (int g = 0; g < 2; g++) {
            union { u32 u[4]; bf16x8 v; } pf[2];
#pragma unroll
            for (int qg = 0; qg < 2; qg++) {
                u32 a0 = (u32)__shfl((int)pk[g][qg][0][0], shA);
                u32 a1 = (u32)__shfl((int)pk[g][qg][0][1], shA);
                u32 a2 = (u32)__shfl((int)pk[g][qg][0][0], shB);
                u32 a3 = (u32)__shfl((int)pk[g][qg][0][1], shB);
                u32 c0 = (u32)__shfl((int)pk[g][qg][1][0], shA);
                u32 c1 = (u32)__shfl((int)pk[g][qg][1][1], shA);
                u32 c2 = (u32)__shfl((int)pk[g][qg][1][0], shB);
                u32 c3 = (u32)__shfl((int)pk[g][qg][1][1], shB);
                pf[qg].u[0] = (quad < 2) ? a0 : c0;
                pf[qg].u[1] = (quad < 2) ? a1 : c1;
                pf[qg].u[2] = (quad < 2) ? a2 : c2;
                pf[qg].u[3] = (quad < 2) ? a3 : c3;
            }
#pragma unroll
            for (int dt = 0; dt < 4; dt++) {
                int drow = dt * 16 + id15;
                bf16x8 vf = *(const bf16x8*)(Vb + drow * 64 +
                                             (((g << 2) | quad) ^ (drow & 7)) * 8);
                accO[dt][0] = __builtin_amdgcn_mfma_f32_16x16x32_bf16(vf, pf[0].v, accO[dt][0], 0, 0, 0);
                accO[dt][1] = __builtin_amdgcn_mfma_f32_16x16x32_bf16(vf, pf[1].v, accO[dt][1], 0, 0, 0);
            }
        }
    }

#pragma unroll
    for (int qg = 0; qg < 2; qg++) {
        float lv = l[qg];
        lv += __shfl_xor(lv, 16);
        lv += __shfl_xor(lv, 32);
        float inv = 1.0f / lv;
#pragma unroll
        for (int dt = 0; dt < 4; dt++) {
            uint2 w;
            w.x = pk_bf2(accO[dt][qg][0] * inv, accO[dt][qg][1] * inv);
            w.y = pk_bf2(accO[dt][qg][2] * inv, accO[dt][qg][3] * inv);
            *(uint2*)(o_buf + ((size_t)b * Tt + wq + qg * 16 + id15) * Cc + h * Dd +
                      dt * 16 + quad * 4) = w;
        }
    }
}

// ---------------- mask tail of d_out (fp32 0/1) ----------------
__global__ void mask_out_k(const int* __restrict__ mask, float* __restrict__ out) {
    int i = blockIdx.x * 256 + threadIdx.x;
    if (i < Bb * Tt) out[i] = mask[i] ? 1.0f : 0.0f;
}

extern "C" void kernel_launch(void* const* d_in, const int* in_sizes, int n_in,
                              void* d_out, int out_size, void* d_ws, size_t ws_size,
                              hipStream_t stream) {
    const float* x  = (const float*)d_in[0];
    const int* mask = (const int*)d_in[1];
    const float* Wq = (const float*)d_in[2];
    const float* bq = (const float*)d_in[3];
    const float* Wk = (const float*)d_in[4];
    const float* bk = (const float*)d_in[5];
    const float* Wv = (const float*)d_in[6];
    const float* bv = (const float*)d_in[7];
    const float* Wp = (const float*)d_in[8];
    const float* bp = (const float*)d_in[9];
    float* out = (float*)d_out;

    size_t sz = (size_t)Bb * Tt * Cc;
    size_t wsz = (size_t)Cc * Cc;
    u16* xT = (u16*)d_ws;
    u16* qb = xT + sz;
    u16* kb = qb + sz;
    u16* vT = kb + sz;
    u16* wq16 = vT + sz;   // wq16/wk16/wv16 contiguous => fused [3072][1024] B matrix
    u16* wk16 = wq16 + wsz;
    u16* wv16 = wk16 + wsz;
    u16* wp16 = wv16 + wsz;
    u16* ob = xT;  // reuse xT: last read by QKV gemm, attn writes after (stream-ordered)

    int cvb = (int)(wsz / 4 / 256);
    cvt_bf16<<<cvb, 256, 0, stream>>>(Wq, wq16, (int)wsz);
    cvt_bf16<<<cvb, 256, 0, stream>>>(Wk, wk16, (int)wsz);
    cvt_bf16<<<cvb, 256, 0, stream>>>(Wv, wv16, (int)wsz);
    cvt_bf16<<<cvb, 256, 0, stream>>>(Wp, wp16, (int)wsz);
    transpose_x<<<dim3(Tt / 32, Cc / 32, Bb), dim3(32, 8), 0, stream>>>(x, xT);
    gemm_qkv<<<dim3(3 * Cc / 128, Bb * Tt / 128), 256, 0, stream>>>(
        xT, wq16, bq, bk, bv, qb, kb, vT);
    attn<<<dim3(Tt / 128, Bb * Hh), 256, 0, stream>>>(qb, kb, vT, mask, ob);
    gemm_proj<<<dim3(Cc / 64, Bb * Tt / 128), 256, 0, stream>>>(ob, wp16, bp, mask, out);
    if (out_size >= Bb * Cc * Tt + Bb * Tt)
        mask_out_k<<<dim3((Bb * Tt + 255) / 256), 256, 0, stream>>>(
            mask, out + (size_t)Bb * Cc * Tt);
}

// Round 7
// 229.721 us; speedup vs baseline: 1.9549x; 1.1233x over previous
//
#include <hip/hip_runtime.h>

typedef unsigned short u16;
typedef unsigned int u32;
typedef short bf16x8 __attribute__((ext_vector_type(8)));
typedef float f32x4 __attribute__((ext_vector_type(4)));

constexpr int Bb = 2, Cc = 1024, Tt = 2048, Hh = 16, Dd = 64;

__device__ __forceinline__ u16 f2bf(float f) {
    union { float f; u32 i; } c; c.f = f;
    u32 u = c.i;
    u32 r = (u + 0x7FFFu + ((u >> 16) & 1u)) >> 16;
    return (u16)r;
}
// pack two fp32 -> bf16x2 (round-half-up)
__device__ __forceinline__ u32 pk_bf2(float lo, float hi) {
    union { float f; u32 i; } a, b; a.f = lo; b.f = hi;
    u32 ua = a.i + 0x8000u, ub = b.i + 0x8000u;
    return (ub & 0xFFFF0000u) | (ua >> 16);
}
// scale packed bf16x2 by 0.125 exactly (fp32 mul is exact for *2^-3; truncation keeps bits)
__device__ __forceinline__ u32 scl2(u32 w) {
    union { float f; u32 i; } lo, hi;
    lo.i = w << 16; hi.i = w & 0xFFFF0000u;
    lo.f *= 0.125f; hi.f *= 0.125f;
    return (hi.i & 0xFFFF0000u) | (lo.i >> 16);
}
// async global->LDS, 16B/lane; lds base wave-uniform, lane L lands at base+16L
__device__ __forceinline__ void gl_lds16(const u16* g, u16* l) {
    __builtin_amdgcn_global_load_lds(
        (const __attribute__((address_space(1))) u32*)(const void*)g,
        (__attribute__((address_space(3))) u32*)(void*)l, 16, 0, 0);
}

// ---------------- fp32 -> bf16, all four weights in one launch ----------------
__global__ __launch_bounds__(256) void cvt_w4(const float* __restrict__ w0,
                                              const float* __restrict__ w1,
                                              const float* __restrict__ w2,
                                              const float* __restrict__ w3,
                                              u16* __restrict__ out) {
    int wsel = blockIdx.y;
    const float* in = (wsel == 0) ? w0 : (wsel == 1) ? w1 : (wsel == 2) ? w2 : w3;
    u16* o = out + (size_t)wsel * Cc * Cc;
    int i = (blockIdx.x * 256 + threadIdx.x) * 4;
    float4 v = *(const float4*)(in + i);
    o[i + 0] = f2bf(v.x);
    o[i + 1] = f2bf(v.y);
    o[i + 2] = f2bf(v.z);
    o[i + 3] = f2bf(v.w);
}

// ---------------- x transpose+convert: fp32 [b][c][t] -> bf16 [b][t][c] ----------------
__global__ __launch_bounds__(256) void transpose_x(const float* __restrict__ x,
                                                   u16* __restrict__ xT) {
    __shared__ u16 tile[32][33];
    int b = blockIdx.z;
    int t0 = blockIdx.x * 32, c0 = blockIdx.y * 32;
    int tx = threadIdx.x, ty = threadIdx.y;
    const float* xb = x + (size_t)b * Cc * Tt;
    u16* xTb = xT + (size_t)b * Tt * Cc;
#pragma unroll
    for (int i = 0; i < 4; i++) {
        int r = ty + i * 8;
        tile[r][tx] = f2bf(xb[(size_t)(c0 + r) * Tt + t0 + tx]);
    }
    __syncthreads();
#pragma unroll
    for (int i = 0; i < 4; i++) {
        int r = ty + i * 8;
        xTb[(size_t)(t0 + r) * Cc + c0 + tx] = tile[tx][r];
    }
}

// ============ fused QKV GEMM: A[4096][1024] x W[3072][1024]^T, 128x128, BK=64 ============
// LDS rows = 64 u16 (128 B = 8 16B-chunks), XOR-swizzle phys = chunk ^ (row&7).
// 16 K-iterations -> 16 barrier drains (halved vs BK=32).
__global__ __launch_bounds__(256) void gemm_qkv(const u16* __restrict__ A,
                                                const u16* __restrict__ Bt,
                                                const float* __restrict__ b0,
                                                const float* __restrict__ b1,
                                                const float* __restrict__ b2,
                                                u16* __restrict__ qb, u16* __restrict__ kb,
                                                u16* __restrict__ vT) {
    constexpr int K = Cc;
    __shared__ u16 Alds[128 * 64];
    __shared__ u16 Blds[128 * 64];
    int n0 = blockIdx.x * 128, m0 = blockIdx.y * 128;
    int tid = threadIdx.x;
    int lane = tid & 63, wave = tid >> 6;
    int quad = lane >> 4, id15 = lane & 15;
    int wm0 = (wave & 1) * 64, wn0 = (wave >> 1) * 64;
    int srow = lane >> 3;                      // 0..7 within 8-row group
    int scol = ((lane & 7) ^ srow) * 8;        // swizzled source chunk (elems)
    int sw = id15 & 7;                         // read-side swizzle

    f32x4 acc[4][4] = {};  // [ni][mi]

    for (int k0 = 0; k0 < K; k0 += 64) {
        __syncthreads();
#pragma unroll
        for (int t = 0; t < 4; t++) {
            int g = wave * 4 + t;              // 8-row group 0..15
            int r = g * 8 + srow;
            gl_lds16(A + (size_t)(m0 + r) * K + k0 + scol, &Alds[g * 512]);
            gl_lds16(Bt + (size_t)(n0 + r) * K + k0 + scol, &Blds[g * 512]);
        }
        __syncthreads();
#pragma unroll
        for (int hf = 0; hf < 2; hf++) {
            bf16x8 af[4], bf[4];
#pragma unroll
            for (int i = 0; i < 4; i++) {
                int c = (((hf << 2) | quad) ^ sw) * 8;
                af[i] = *(const bf16x8*)(&Alds[(wm0 + i * 16 + id15) * 64 + c]);
                bf[i] = *(const bf16x8*)(&Blds[(wn0 + i * 16 + id15) * 64 + c]);
            }
#pragma unroll
            for (int ni = 0; ni < 4; ni++)
#pragma unroll
                for (int mi = 0; mi < 4; mi++)
                    acc[ni][mi] = __builtin_amdgcn_mfma_f32_16x16x32_bf16(
                        bf[ni], af[mi], acc[ni][mi], 0, 0, 0);
        }
    }

    int bb = m0 >> 11;
    int mt0 = (m0 & 2047) + wm0;
#pragma unroll
    for (int ni = 0; ni < 4; ni++) {
        int nr = n0 + wn0 + ni * 16 + quad * 4;
        int sect = nr >> 10;
        int nn = nr & 1023;
        int h = nn >> 6, d0 = nn & 63;
        const float* bp_ = (sect == 0) ? b0 : (sect == 1) ? b1 : b2;
        float4 bv4 = *(const float4*)(bp_ + nn);
        if (sect < 2) {
            u16* dst = ((sect == 0) ? qb : kb) + ((size_t)bb * Hh + h) * Tt * (size_t)Dd;
#pragma unroll
            for (int mi = 0; mi < 4; mi++) {
                int mt = mt0 + mi * 16 + id15;
                uint2 w;
                w.x = pk_bf2(acc[ni][mi][0] + bv4.x, acc[ni][mi][1] + bv4.y);
                w.y = pk_bf2(acc[ni][mi][2] + bv4.z, acc[ni][mi][3] + bv4.w);
                *(uint2*)(dst + (size_t)mt * Dd + d0) = w;
            }
        } else {
            u16* dst = vT + ((size_t)bb * Hh + h) * Dd * (size_t)Tt;
#pragma unroll
            for (int mi = 0; mi < 4; mi++) {
                int mt = mt0 + mi * 16 + id15;
                dst[(size_t)(d0 + 0) * Tt + mt] = f2bf(acc[ni][mi][0] + bv4.x);
                dst[(size_t)(d0 + 1) * Tt + mt] = f2bf(acc[ni][mi][1] + bv4.y);
                dst[(size_t)(d0 + 2) * Tt + mt] = f2bf(acc[ni][mi][2] + bv4.z);
                dst[(size_t)(d0 + 3) * Tt + mt] = f2bf(acc[ni][mi][3] + bv4.w);
            }
        }
    }
}

// ============ proj GEMM: A[4096][1024] x Wp[1024][1024]^T, 64n x 128m, BK=64 ============
__global__ __launch_bounds__(256) void gemm_proj(const u16* __restrict__ A,
                                                 const u16* __restrict__ Bt,
                                                 const float* __restrict__ b0,
                                                 const int* __restrict__ mask,
                                                 float* __restrict__ out) {
    constexpr int K = Cc;
    __shared__ u16 Alds[128 * 64];
    __shared__ u16 Blds[64 * 64];
    int n0 = blockIdx.x * 64, m0 = blockIdx.y * 128;
    int tid = threadIdx.x;
    int lane = tid & 63, wave = tid >> 6;
    int quad = lane >> 4, id15 = lane & 15;
    int wn0 = (wave & 1) * 32, wm0 = (wave >> 1) * 64;
    int srow = lane >> 3;
    int scol = ((lane & 7) ^ srow) * 8;
    int sw = id15 & 7;

    f32x4 acc[2][4] = {};

    for (int k0 = 0; k0 < K; k0 += 64) {
        __syncthreads();
#pragma unroll
        for (int t = 0; t < 4; t++) {
            int g = wave * 4 + t;
            gl_lds16(A + (size_t)(m0 + g * 8 + srow) * K + k0 + scol, &Alds[g * 512]);
        }
#pragma unroll
        for (int t = 0; t < 2; t++) {
            int g = wave * 2 + t;
            gl_lds16(Bt + (size_t)(n0 + g * 8 + srow) * K + k0 + scol, &Blds[g * 512]);
        }
        __syncthreads();
#pragma unroll
        for (int hf = 0; hf < 2; hf++) {
            bf16x8 af[4], bf[2];
            int c = (((hf << 2) | quad) ^ sw) * 8;
#pragma unroll
            for (int i = 0; i < 4; i++)
                af[i] = *(const bf16x8*)(&Alds[(wm0 + i * 16 + id15) * 64 + c]);
#pragma unroll
            for (int i = 0; i < 2; i++)
                bf[i] = *(const bf16x8*)(&Blds[(wn0 + i * 16 + id15) * 64 + c]);
#pragma unroll
            for (int ni = 0; ni < 2; ni++)
#pragma unroll
                for (int mi = 0; mi < 4; mi++)
                    acc[ni][mi] = __builtin_amdgcn_mfma_f32_16x16x32_bf16(
                        bf[ni], af[mi], acc[ni][mi], 0, 0, 0);
        }
    }

    int bb = m0 >> 11;
    int mt0 = (m0 & 2047) + wm0;
#pragma unroll
    for (int ni = 0; ni < 2; ni++) {
        int nr = n0 + wn0 + ni * 16 + quad * 4;
        float4 bv4 = *(const float4*)(b0 + nr);
#pragma unroll
        for (int mi = 0; mi < 4; mi++) {
            int m = mt0 + mi * 16 + id15;
            int mg = (bb << 11) + m;
            float mm = (float)mask[mg];
            float* o = out + ((size_t)bb * Cc + nr) * Tt + m;
            o[0 * Tt] = (acc[ni][mi][0] + bv4.x) * mm;
            o[1 * Tt] = (acc[ni][mi][1] + bv4.y) * mm;
            o[2 * Tt] = (acc[ni][mi][2] + bv4.z) * mm;
            o[3 * Tt] = (acc[ni][mi][3] + bv4.w) * mm;
        }
    }
}

// ---------------- staged flash attention: Q-tile 128, 128-key LDS chunks ----------------
// 16 chunks -> 16 barriers (halved). Scale folded into Q. Mask pre-converted to
// float in LDS. K rows 128B (8 chunks, XOR swz row&7); V rows 256B (16 chunks,
// XOR swz of low 3 bits by d&7).
__global__ __launch_bounds__(256) void attn(const u16* __restrict__ q,
                                            const u16* __restrict__ kk,
                                            const u16* __restrict__ vT,
                                            const int* __restrict__ mask,
                                            u16* __restrict__ o_buf) {
    __shared__ u16 Kl[2][128 * 64];
    __shared__ u16 Vl[2][64 * 128];
    __shared__ float mkf[Tt];
    int bh = blockIdx.y;
    int b = bh >> 4, h = bh & 15;
    int t0 = blockIdx.x * 128;
    int tid = threadIdx.x;
    int lane = tid & 63, wave = tid >> 6;
    int quad = lane >> 4, id15 = lane & 15;
    int wq = t0 + wave * 32;
    const u16* qb = q + (size_t)bh * Tt * Dd;
    const u16* kb = kk + (size_t)bh * Tt * Dd;
    const u16* vb = vT + (size_t)bh * Dd * Tt;
    const int* mrow = mask + b * Tt;

    // mask -> float LDS (once per block)
#pragma unroll
    for (int i = 0; i < 8; i++) mkf[tid * 8 + i] = (float)mrow[tid * 8 + i];

    // Q fragments with 0.125 scale folded in (exact)
    union { uint4 r; bf16x8 v; } qf[2][2];
#pragma unroll
    for (int qg = 0; qg < 2; qg++)
#pragma unroll
        for (int hf = 0; hf < 2; hf++) {
            uint4 r = *(const uint4*)(qb + (size_t)(wq + qg * 16 + id15) * Dd +
                                      hf * 32 + quad * 8);
            qf[qg][hf].r.x = scl2(r.x);
            qf[qg][hf].r.y = scl2(r.y);
            qf[qg][hf].r.z = scl2(r.z);
            qf[qg][hf].r.w = scl2(r.w);
        }

    // staging geometry
    int srowK = lane >> 3;                          // 0..7
    int scolK = ((lane & 7) ^ srowK) * 8;           // K: 8-chunk rows
    int srowV = lane >> 4;                          // 0..3
    int sw = id15 & 7;

    float l[2] = {0.0f, 0.0f};
    f32x4 accO[4][2] = {};

    // prologue: stage chunk 0 into buf 0
#pragma unroll
    for (int t = 0; t < 4; t++) {
        int g = wave * 4 + t;
        gl_lds16(kb + (size_t)(g * 8 + srowK) * Dd + scolK, &Kl[0][g * 512]);
        int d = g * 4 + srowV;
        int sc = (lane & 15) ^ (4 * (g & 1) + srowV);
        gl_lds16(vb + (size_t)d * Tt + sc * 8, &Vl[0][g * 512]);
    }

    int shA = ((quad & 1) * 2) * 16 + id15;
    int shB = shA + 16;

    for (int c = 0; c < 16; c++) {
        int j0 = c * 128;
        __syncthreads();
        if (c < 15) {
            int bb = (c + 1) & 1, jn = j0 + 128;
#pragma unroll
            for (int t = 0; t < 4; t++) {
                int g = wave * 4 + t;
                gl_lds16(kb + (size_t)(jn + g * 8 + srowK) * Dd + scolK, &Kl[bb][g * 512]);
                int d = g * 4 + srowV;
                int sc = (lane & 15) ^ (4 * (g & 1) + srowV);
                gl_lds16(vb + (size_t)d * Tt + jn + sc * 8, &Vl[bb][g * 512]);
            }
        }
        const u16* Kb = Kl[c & 1];
        const u16* Vb = Vl[c & 1];

        // S^T for 128 keys x 32 queries (scale already in Q)
        f32x4 st[8][2] = {};
#pragma unroll
        for (int kt = 0; kt < 8; kt++) {
            int krow = kt * 16 + id15;
#pragma unroll
            for (int hf = 0; hf < 2; hf++) {
                bf16x8 kf = *(const bf16x8*)(Kb + krow * 64 + (((hf << 2) | quad) ^ sw) * 8);
                st[kt][0] = __builtin_amdgcn_mfma_f32_16x16x32_bf16(kf, qf[0][hf].v, st[kt][0], 0, 0, 0);
                st[kt][1] = __builtin_amdgcn_mfma_f32_16x16x32_bf16(kf, qf[1][hf].v, st[kt][1], 0, 0, 0);
            }
        }

        // exp + mask + pack
        u32 pkk[4][2][2][2];
#pragma unroll
        for (int kt = 0; kt < 8; kt++) {
            float4 fm = *(const float4*)(&mkf[j0 + kt * 16 + quad * 4]);
#pragma unroll
            for (int qg = 0; qg < 2; qg++) {
                float p0 = __expf(st[kt][qg][0]) * fm.x;
                float p1 = __expf(st[kt][qg][1]) * fm.y;
                float p2 = __expf(st[kt][qg][2]) * fm.z;
                float p3 = __expf(st[kt][qg][3]) * fm.w;
                l[qg] += (p0 + p1) + (p2 + p3);
                pkk[kt >> 1][qg][kt & 1][0] = pk_bf2(p0, p1);
                pkk[kt >> 1][qg][kt & 1][1] = pk_bf2(p2, p3);
            }
        }

        // per 32-key group: P^T B-frag via shfl, then PV
#pragma unroll
        for (int g = 0; g < 4; g++) {
            union { u32 u[4]; bf16x8 v; } pf[2];
#pragma unroll
            for (int qg = 0; qg < 2; qg++) {
                u32 a0 = (u32)__shfl((int)pkk[g][qg][0][0], shA);
                u32 a1 = (u32)__shfl((int)pkk[g][qg][0][1], shA);
                u32 a2 = (u32)__shfl((int)pkk[g][qg][0][0], shB);
                u32 a3 = (u32)__shfl((int)pkk[g][qg][0][1], shB);
                u32 c0 = (u32)__shfl((int)pkk[g][qg][1][0], shA);
                u32 c1 = (u32)__shfl((int)pkk[g][qg][1][1], shA);
                u32 c2 = (u32)__shfl((int)pkk[g][qg][1][0], shB);
                u32 c3 = (u32)__shfl((int)pkk[g][qg][1][1], shB);
                pf[qg].u[0] = (quad < 2) ? a0 : c0;
                pf[qg].u[1] = (quad < 2) ? a1 : c1;
                pf[qg].u[2] = (quad < 2) ? a2 : c2;
                pf[qg].u[3] = (quad < 2) ? a3 : c3;
            }
#pragma unroll
            for (int dt = 0; dt < 4; dt++) {
                int drow = dt * 16 + id15;
                bf16x8 vf = *(const bf16x8*)(Vb + drow * 128 + (((g << 2) | quad) ^ sw) * 8);
                accO[dt][0] = __builtin_amdgcn_mfma_f32_16x16x32_bf16(vf, pf[0].v, accO[dt][0], 0, 0, 0);
                accO[dt][1] = __builtin_amdgcn_mfma_f32_16x16x32_bf16(vf, pf[1].v, accO[dt][1], 0, 0, 0);
            }
        }
    }

#pragma unroll
    for (int qg = 0; qg < 2; qg++) {
        float lv = l[qg];
        lv += __shfl_xor(lv, 16);
        lv += __shfl_xor(lv, 32);
        float inv = 1.0f / lv;
#pragma unroll
        for (int dt = 0; dt < 4; dt++) {
            uint2 w;
            w.x = pk_bf2(accO[dt][qg][0] * inv, accO[dt][qg][1] * inv);
            w.y = pk_bf2(accO[dt][qg][2] * inv, accO[dt][qg][3] * inv);
            *(uint2*)(o_buf + ((size_t)b * Tt + wq + qg * 16 + id15) * Cc + h * Dd +
                      dt * 16 + quad * 4) = w;
        }
    }
}

// ---------------- mask tail of d_out (fp32 0/1) ----------------
__global__ void mask_out_k(const int* __restrict__ mask, float* __restrict__ out) {
    int i = blockIdx.x * 256 + threadIdx.x;
    if (i < Bb * Tt) out[i] = mask[i] ? 1.0f : 0.0f;
}

extern "C" void kernel_launch(void* const* d_in, const int* in_sizes, int n_in,
                              void* d_out, int out_size, void* d_ws, size_t ws_size,
                              hipStream_t stream) {
    const float* x  = (const float*)d_in[0];
    const int* mask = (const int*)d_in[1];
    const float* Wq = (const float*)d_in[2];
    const float* bq = (const float*)d_in[3];
    const float* Wk = (const float*)d_in[4];
    const float* bk = (const float*)d_in[5];
    const float* Wv = (const float*)d_in[6];
    const float* bv = (const float*)d_in[7];
    const float* Wp = (const float*)d_in[8];
    const float* bp = (const float*)d_in[9];
    float* out = (float*)d_out;

    size_t sz = (size_t)Bb * Tt * Cc;
    size_t wsz = (size_t)Cc * Cc;
    u16* xT = (u16*)d_ws;
    u16* qb = xT + sz;
    u16* kb = qb + sz;
    u16* vT = kb + sz;
    u16* wq16 = vT + sz;   // wq16/wk16/wv16 contiguous => fused [3072][1024] B matrix
    u16* wp16 = wq16 + 3 * wsz;
    u16* ob = xT;  // reuse xT: last read by QKV gemm, attn writes after (stream-ordered)

    cvt_w4<<<dim3((int)(wsz / 1024), 4), 256, 0, stream>>>(Wq, Wk, Wv, Wp, wq16);
    transpose_x<<<dim3(Tt / 32, Cc / 32, Bb), dim3(32, 8), 0, stream>>>(x, xT);
    gemm_qkv<<<dim3(3 * Cc / 128, Bb * Tt / 128), 256, 0, stream>>>(
        xT, wq16, bq, bk, bv, qb, kb, vT);
    attn<<<dim3(Tt / 128, Bb * Hh), 256, 0, stream>>>(qb, kb, vT, mask, ob);
    gemm_proj<<<dim3(Cc / 64, Bb * Tt / 128), 256, 0, stream>>>(ob, wp16, bp, mask, out);
    if (out_size >= Bb * Cc * Tt + Bb * Tt)
        mask_out_k<<<dim3((Bb * Tt + 255) / 256), 256, 0, stream>>>(
            mask, out + (size_t)Bb * Cc * Tt);
}

// Round 8
// 184.845 us; speedup vs baseline: 2.4295x; 1.2428x over previous
//
#include <hip/hip_runtime.h>

typedef unsigned short u16;
typedef unsigned int u32;
typedef short bf16x8 __attribute__((ext_vector_type(8)));
typedef float f32x4 __attribute__((ext_vector_type(4)));

constexpr int Bb = 2, Cc = 1024, Tt = 2048, Hh = 16, Dd = 64;

__device__ __forceinline__ u16 f2bf(float f) {
    union { float f; u32 i; } c; c.f = f;
    u32 u = c.i;
    u32 r = (u + 0x7FFFu + ((u >> 16) & 1u)) >> 16;
    return (u16)r;
}
__device__ __forceinline__ u32 pk_bf2(float lo, float hi) {
    union { float f; u32 i; } a, b; a.f = lo; b.f = hi;
    u32 ua = a.i + 0x8000u, ub = b.i + 0x8000u;
    return (ub & 0xFFFF0000u) | (ua >> 16);
}
// scale packed bf16x2 by 0.125 exactly
__device__ __forceinline__ u32 scl2(u32 w) {
    union { float f; u32 i; } lo, hi;
    lo.i = w << 16; hi.i = w & 0xFFFF0000u;
    lo.f *= 0.125f; hi.f *= 0.125f;
    return (hi.i & 0xFFFF0000u) | (lo.i >> 16);
}
__device__ __forceinline__ void gl_lds16(const u16* g, u16* l) {
    __builtin_amdgcn_global_load_lds(
        (const __attribute__((address_space(1))) u32*)(const void*)g,
        (__attribute__((address_space(3))) u32*)(void*)l, 16, 0, 0);
}

// ---------------- per-batch mask scan: pfx (exclusive), tmap (slot->t), nk ----------------
__global__ __launch_bounds__(256) void scan_mask(const int* __restrict__ mask,
                                                 int* __restrict__ pfx,
                                                 int* __restrict__ tmap,
                                                 int* __restrict__ nk) {
    __shared__ int part[256];
    int b = blockIdx.x;
    const int* m = mask + b * Tt;
    int t8 = threadIdx.x * 8;
    int v[8], s = 0;
#pragma unroll
    for (int i = 0; i < 8; i++) { v[i] = m[t8 + i] ? 1 : 0; s += v[i]; }
    part[threadIdx.x] = s;
    __syncthreads();
    for (int off = 1; off < 256; off <<= 1) {
        int val = (threadIdx.x >= off) ? part[threadIdx.x - off] : 0;
        __syncthreads();
        part[threadIdx.x] += val;
        __syncthreads();
    }
    int run = part[threadIdx.x] - s;  // exclusive base
#pragma unroll
    for (int i = 0; i < 8; i++) {
        pfx[b * Tt + t8 + i] = run;
        if (v[i]) { tmap[b * Tt + run] = t8 + i; run++; }
    }
    if (threadIdx.x == 255) nk[b] = part[255];
}

// ---------------- fp32 -> bf16, all four weights in one launch ----------------
__global__ __launch_bounds__(256) void cvt_w4(const float* __restrict__ w0,
                                              const float* __restrict__ w1,
                                              const float* __restrict__ w2,
                                              const float* __restrict__ w3,
                                              u16* __restrict__ out) {
    int wsel = blockIdx.y;
    const float* in = (wsel == 0) ? w0 : (wsel == 1) ? w1 : (wsel == 2) ? w2 : w3;
    u16* o = out + (size_t)wsel * Cc * Cc;
    int i = (blockIdx.x * 256 + threadIdx.x) * 4;
    float4 v = *(const float4*)(in + i);
    o[i + 0] = f2bf(v.x);
    o[i + 1] = f2bf(v.y);
    o[i + 2] = f2bf(v.z);
    o[i + 3] = f2bf(v.w);
}

// ------- x transpose+convert+COMPACT: fp32 [b][c][t] -> bf16 xTc[b][pfx[t]][c] -------
__global__ __launch_bounds__(256) void transpose_x(const float* __restrict__ x,
                                                   const int* __restrict__ mask,
                                                   const int* __restrict__ pfx,
                                                   u16* __restrict__ xT) {
    __shared__ u16 tile[32][33];
    int b = blockIdx.z;
    int t0 = blockIdx.x * 32, c0 = blockIdx.y * 32;
    int tx = threadIdx.x, ty = threadIdx.y;
    const float* xb = x + (size_t)b * Cc * Tt;
    u16* xTb = xT + (size_t)b * Tt * Cc;
#pragma unroll
    for (int i = 0; i < 4; i++) {
        int r = ty + i * 8;
        tile[r][tx] = f2bf(xb[(size_t)(c0 + r) * Tt + t0 + tx]);
    }
    __syncthreads();
#pragma unroll
    for (int i = 0; i < 4; i++) {
        int r = ty + i * 8;
        int t = t0 + r;
        if (mask[b * Tt + t]) {
            int slot = pfx[b * Tt + t];
            xTb[(size_t)slot * Cc + c0 + tx] = tile[tx][r];
        }
    }
}

// ============ fused QKV GEMM on COMPACTED rows: 128x128, BK=64 ============
// Tiles fully beyond nk[b] exit early. Outputs land in compacted slot space.
__global__ __launch_bounds__(256) void gemm_qkv(const u16* __restrict__ A,
                                                const u16* __restrict__ Bt,
                                                const float* __restrict__ b0,
                                                const float* __restrict__ b1,
                                                const float* __restrict__ b2,
                                                const int* __restrict__ nk,
                                                u16* __restrict__ qb, u16* __restrict__ kb,
                                                u16* __restrict__ vT) {
    constexpr int K = Cc;
    __shared__ u16 Alds[128 * 64];
    __shared__ u16 Blds[128 * 64];
    int n0 = blockIdx.x * 128, m0 = blockIdx.y * 128;
    int bb = m0 >> 11;
    if ((m0 & 2047) >= nk[bb]) return;   // whole tile is dead rows
    int tid = threadIdx.x;
    int lane = tid & 63, wave = tid >> 6;
    int quad = lane >> 4, id15 = lane & 15;
    int wm0 = (wave & 1) * 64, wn0 = (wave >> 1) * 64;
    int srow = lane >> 3;
    int scol = ((lane & 7) ^ srow) * 8;
    int sw = id15 & 7;

    f32x4 acc[4][4] = {};  // [ni][mi]

    for (int k0 = 0; k0 < K; k0 += 64) {
        __syncthreads();
#pragma unroll
        for (int t = 0; t < 4; t++) {
            int g = wave * 4 + t;
            int r = g * 8 + srow;
            gl_lds16(A + (size_t)(m0 + r) * K + k0 + scol, &Alds[g * 512]);
            gl_lds16(Bt + (size_t)(n0 + r) * K + k0 + scol, &Blds[g * 512]);
        }
        __syncthreads();
#pragma unroll
        for (int hf = 0; hf < 2; hf++) {
            bf16x8 af[4], bf[4];
#pragma unroll
            for (int i = 0; i < 4; i++) {
                int c = (((hf << 2) | quad) ^ sw) * 8;
                af[i] = *(const bf16x8*)(&Alds[(wm0 + i * 16 + id15) * 64 + c]);
                bf[i] = *(const bf16x8*)(&Blds[(wn0 + i * 16 + id15) * 64 + c]);
            }
#pragma unroll
            for (int ni = 0; ni < 4; ni++)
#pragma unroll
                for (int mi = 0; mi < 4; mi++)
                    acc[ni][mi] = __builtin_amdgcn_mfma_f32_16x16x32_bf16(
                        bf[ni], af[mi], acc[ni][mi], 0, 0, 0);
        }
    }

    int mt0 = (m0 & 2047) + wm0;
#pragma unroll
    for (int ni = 0; ni < 4; ni++) {
        int nr = n0 + wn0 + ni * 16 + quad * 4;
        int sect = nr >> 10;
        int nn = nr & 1023;
        int h = nn >> 6, d0 = nn & 63;
        const float* bp_ = (sect == 0) ? b0 : (sect == 1) ? b1 : b2;
        float4 bv4 = *(const float4*)(bp_ + nn);
        if (sect < 2) {
            u16* dst = ((sect == 0) ? qb : kb) + ((size_t)bb * Hh + h) * Tt * (size_t)Dd;
#pragma unroll
            for (int mi = 0; mi < 4; mi++) {
                int mt = mt0 + mi * 16 + id15;
                uint2 w;
                w.x = pk_bf2(acc[ni][mi][0] + bv4.x, acc[ni][mi][1] + bv4.y);
                w.y = pk_bf2(acc[ni][mi][2] + bv4.z, acc[ni][mi][3] + bv4.w);
                *(uint2*)(dst + (size_t)mt * Dd + d0) = w;
            }
        } else {
            u16* dst = vT + ((size_t)bb * Hh + h) * Dd * (size_t)Tt;
#pragma unroll
            for (int mi = 0; mi < 4; mi++) {
                int mt = mt0 + mi * 16 + id15;
                dst[(size_t)(d0 + 0) * Tt + mt] = f2bf(acc[ni][mi][0] + bv4.x);
                dst[(size_t)(d0 + 1) * Tt + mt] = f2bf(acc[ni][mi][1] + bv4.y);
                dst[(size_t)(d0 + 2) * Tt + mt] = f2bf(acc[ni][mi][2] + bv4.z);
                dst[(size_t)(d0 + 3) * Tt + mt] = f2bf(acc[ni][mi][3] + bv4.w);
            }
        }
    }
}

// ============ proj GEMM (UNCHANGED, full-M): 64n x 128m, BK=64 ============
__global__ __launch_bounds__(256) void gemm_proj(const u16* __restrict__ A,
                                                 const u16* __restrict__ Bt,
                                                 const float* __restrict__ b0,
                                                 const int* __restrict__ mask,
                                                 float* __restrict__ out) {
    constexpr int K = Cc;
    __shared__ u16 Alds[128 * 64];
    __shared__ u16 Blds[64 * 64];
    int n0 = blockIdx.x * 64, m0 = blockIdx.y * 128;
    int tid = threadIdx.x;
    int lane = tid & 63, wave = tid >> 6;
    int quad = lane >> 4, id15 = lane & 15;
    int wn0 = (wave & 1) * 32, wm0 = (wave >> 1) * 64;
    int srow = lane >> 3;
    int scol = ((lane & 7) ^ srow) * 8;
    int sw = id15 & 7;

    f32x4 acc[2][4] = {};

    for (int k0 = 0; k0 < K; k0 += 64) {
        __syncthreads();
#pragma unroll
        for (int t = 0; t < 4; t++) {
            int g = wave * 4 + t;
            gl_lds16(A + (size_t)(m0 + g * 8 + srow) * K + k0 + scol, &Alds[g * 512]);
        }
#pragma unroll
        for (int t = 0; t < 2; t++) {
            int g = wave * 2 + t;
            gl_lds16(Bt + (size_t)(n0 + g * 8 + srow) * K + k0 + scol, &Blds[g * 512]);
        }
        __syncthreads();
#pragma unroll
        for (int hf = 0; hf < 2; hf++) {
            bf16x8 af[4], bf[2];
            int c = (((hf << 2) | quad) ^ sw) * 8;
#pragma unroll
            for (int i = 0; i < 4; i++)
                af[i] = *(const bf16x8*)(&Alds[(wm0 + i * 16 + id15) * 64 + c]);
#pragma unroll
            for (int i = 0; i < 2; i++)
                bf[i] = *(const bf16x8*)(&Blds[(wn0 + i * 16 + id15) * 64 + c]);
#pragma unroll
            for (int ni = 0; ni < 2; ni++)
#pragma unroll
                for (int mi = 0; mi < 4; mi++)
                    acc[ni][mi] = __builtin_amdgcn_mfma_f32_16x16x32_bf16(
                        bf[ni], af[mi], acc[ni][mi], 0, 0, 0);
        }
    }

    int bb = m0 >> 11;
    int mt0 = (m0 & 2047) + wm0;
#pragma unroll
    for (int ni = 0; ni < 2; ni++) {
        int nr = n0 + wn0 + ni * 16 + quad * 4;
        float4 bv4 = *(const float4*)(b0 + nr);
#pragma unroll
        for (int mi = 0; mi < 4; mi++) {
            int m = mt0 + mi * 16 + id15;
            int mg = (bb << 11) + m;
            float mm = (float)mask[mg];
            float* o = out + ((size_t)bb * Cc + nr) * Tt + m;
            o[0 * Tt] = (acc[ni][mi][0] + bv4.x) * mm;
            o[1 * Tt] = (acc[ni][mi][1] + bv4.y) * mm;
            o[2 * Tt] = (acc[ni][mi][2] + bv4.z) * mm;
            o[3 * Tt] = (acc[ni][mi][3] + bv4.w) * mm;
        }
    }
}

// ---------------- staged flash attention on COMPACTED q/k/v ----------------
// Loop over nk[b] keys (no mask logic; final chunk selects slot<nk before exp).
// O scattered back to original t rows via tmap; dead query slots predicated out.
__global__ __launch_bounds__(256) void attn(const u16* __restrict__ q,
                                            const u16* __restrict__ kk,
                                            const u16* __restrict__ vT,
                                            const int* __restrict__ tmap,
                                            const int* __restrict__ nk,
                                            u16* __restrict__ o_buf) {
    __shared__ u16 Kl[2][128 * 64];
    __shared__ u16 Vl[2][64 * 128];
    int bh = blockIdx.y;
    int b = bh >> 4, h = bh & 15;
    int t0 = blockIdx.x * 128;
    int nkb = nk[b];
    if (t0 >= nkb) return;   // whole query tile is dead
    int tid = threadIdx.x;
    int lane = tid & 63, wave = tid >> 6;
    int quad = lane >> 4, id15 = lane & 15;
    int wq = t0 + wave * 32;
    const u16* qb = q + (size_t)bh * Tt * Dd;
    const u16* kb = kk + (size_t)bh * Tt * Dd;
    const u16* vb = vT + (size_t)bh * Dd * Tt;

    // Q fragments with 0.125 scale folded in
    union { uint4 r; bf16x8 v; } qf[2][2];
#pragma unroll
    for (int qg = 0; qg < 2; qg++)
#pragma unroll
        for (int hf = 0; hf < 2; hf++) {
            uint4 r = *(const uint4*)(qb + (size_t)(wq + qg * 16 + id15) * Dd +
                                      hf * 32 + quad * 8);
            qf[qg][hf].r.x = scl2(r.x);
            qf[qg][hf].r.y = scl2(r.y);
            qf[qg][hf].r.z = scl2(r.z);
            qf[qg][hf].r.w = scl2(r.w);
        }

    int srowK = lane >> 3;
    int scolK = ((lane & 7) ^ srowK) * 8;
    int srowV = lane >> 4;
    int sw = id15 & 7;

    float l[2] = {0.0f, 0.0f};
    f32x4 accO[4][2] = {};

    // prologue: stage chunk 0 into buf 0
#pragma unroll
    for (int t = 0; t < 4; t++) {
        int g = wave * 4 + t;
        gl_lds16(kb + (size_t)(g * 8 + srowK) * Dd + scolK, &Kl[0][g * 512]);
        int d = g * 4 + srowV;
        int sc = (lane & 15) ^ (4 * (g & 1) + srowV);
        gl_lds16(vb + (size_t)d * Tt + sc * 8, &Vl[0][g * 512]);
    }

    int shA = ((quad & 1) * 2) * 16 + id15;
    int shB = shA + 16;

    int cbuf = 0;
    for (int j0 = 0; j0 < nkb; j0 += 128, cbuf ^= 1) {
        __syncthreads();
        if (j0 + 128 < nkb) {
            int bb = cbuf ^ 1, jn = j0 + 128;
#pragma unroll
            for (int t = 0; t < 4; t++) {
                int g = wave * 4 + t;
                gl_lds16(kb + (size_t)(jn + g * 8 + srowK) * Dd + scolK, &Kl[bb][g * 512]);
                int d = g * 4 + srowV;
                int sc = (lane & 15) ^ (4 * (g & 1) + srowV);
                gl_lds16(vb + (size_t)d * Tt + jn + sc * 8, &Vl[bb][g * 512]);
            }
        }
        const u16* Kb = Kl[cbuf];
        const u16* Vb = Vl[cbuf];

        f32x4 st[8][2] = {};
#pragma unroll
        for (int kt = 0; kt < 8; kt++) {
            int krow = kt * 16 + id15;
#pragma unroll
            for (int hf = 0; hf < 2; hf++) {
                bf16x8 kf = *(const bf16x8*)(Kb + krow * 64 + (((hf << 2) | quad) ^ sw) * 8);
                st[kt][0] = __builtin_amdgcn_mfma_f32_16x16x32_bf16(kf, qf[0][hf].v, st[kt][0], 0, 0, 0);
                st[kt][1] = __builtin_amdgcn_mfma_f32_16x16x32_bf16(kf, qf[1][hf].v, st[kt][1], 0, 0, 0);
            }
        }

        // tail chunk: dead key slots -> -inf before exp
        if (j0 + 128 > nkb) {
#pragma unroll
            for (int kt = 0; kt < 8; kt++) {
                int jb = j0 + kt * 16 + quad * 4;
#pragma unroll
                for (int qg = 0; qg < 2; qg++)
#pragma unroll
                    for (int r = 0; r < 4; r++)
                        if (jb + r >= nkb) st[kt][qg][r] = -1e30f;
            }
        }

        u32 pkk[4][2][2][2];
#pragma unroll
        for (int kt = 0; kt < 8; kt++) {
#pragma unroll
            for (int qg = 0; qg < 2; qg++) {
                float p0 = __expf(st[kt][qg][0]);
                float p1 = __expf(st[kt][qg][1]);
                float p2 = __expf(st[kt][qg][2]);
                float p3 = __expf(st[kt][qg][3]);
                l[qg] += (p0 + p1) + (p2 + p3);
                pkk[kt >> 1][qg][kt & 1][0] = pk_bf2(p0, p1);
                pkk[kt >> 1][qg][kt & 1][1] = pk_bf2(p2, p3);
            }
        }

#pragma unroll
        for (int g = 0; g < 4; g++) {
            union { u32 u[4]; bf16x8 v; } pf[2];
#pragma unroll
            for (int qg = 0; qg < 2; qg++) {
                u32 a0 = (u32)__shfl((int)pkk[g][qg][0][0], shA);
                u32 a1 = (u32)__shfl((int)pkk[g][qg][0][1], shA);
                u32 a2 = (u32)__shfl((int)pkk[g][qg][0][0], shB);
                u32 a3 = (u32)__shfl((int)pkk[g][qg][0][1], shB);
                u32 c0 = (u32)__shfl((int)pkk[g][qg][1][0], shA);
                u32 c1 = (u32)__shfl((int)pkk[g][qg][1][1], shA);
                u32 c2 = (u32)__shfl((int)pkk[g][qg][1][0], shB);
                u32 c3 = (u32)__shfl((int)pkk[g][qg][1][1], shB);
                pf[qg].u[0] = (quad < 2) ? a0 : c0;
                pf[qg].u[1] = (quad < 2) ? a1 : c1;
                pf[qg].u[2] = (quad < 2) ? a2 : c2;
                pf[qg].u[3] = (quad < 2) ? a3 : c3;
            }
#pragma unroll
            for (int dt = 0; dt < 4; dt++) {
                int drow = dt * 16 + id15;
                bf16x8 vf = *(const bf16x8*)(Vb + drow * 128 + (((g << 2) | quad) ^ sw) * 8);
                accO[dt][0] = __builtin_amdgcn_mfma_f32_16x16x32_bf16(vf, pf[0].v, accO[dt][0], 0, 0, 0);
                accO[dt][1] = __builtin_amdgcn_mfma_f32_16x16x32_bf16(vf, pf[1].v, accO[dt][1], 0, 0, 0);
            }
        }
    }

#pragma unroll
    for (int qg = 0; qg < 2; qg++) {
        int slot = wq + qg * 16 + id15;
        bool ok = slot < nkb;
        int torig = ok ? tmap[b * Tt + slot] : 0;
        float lv = l[qg];
        lv += __shfl_xor(lv, 16);
        lv += __shfl_xor(lv, 32);
        float inv = 1.0f / lv;
        if (ok) {
#pragma unroll
            for (int dt = 0; dt < 4; dt++) {
                uint2 w;
                w.x = pk_bf2(accO[dt][qg][0] * inv, accO[dt][qg][1] * inv);
                w.y = pk_bf2(accO[dt][qg][2] * inv, accO[dt][qg][3] * inv);
                *(uint2*)(o_buf + ((size_t)b * Tt + torig) * Cc + h * Dd +
                          dt * 16 + quad * 4) = w;
            }
        }
    }
}

// ---------------- mask tail of d_out (fp32 0/1) ----------------
__global__ void mask_out_k(const int* __restrict__ mask, float* __restrict__ out) {
    int i = blockIdx.x * 256 + threadIdx.x;
    if (i < Bb * Tt) out[i] = mask[i] ? 1.0f : 0.0f;
}

extern "C" void kernel_launch(void* const* d_in, const int* in_sizes, int n_in,
                              void* d_out, int out_size, void* d_ws, size_t ws_size,
                              hipStream_t stream) {
    const float* x  = (const float*)d_in[0];
    const int* mask = (const int*)d_in[1];
    const float* Wq = (const float*)d_in[2];
    const float* bq = (const float*)d_in[3];
    const float* Wk = (const float*)d_in[4];
    const float* bk = (const float*)d_in[5];
    const float* Wv = (const float*)d_in[6];
    const float* bv = (const float*)d_in[7];
    const float* Wp = (const float*)d_in[8];
    const float* bp = (const float*)d_in[9];
    float* out = (float*)d_out;

    size_t sz = (size_t)Bb * Tt * Cc;
    size_t wsz = (size_t)Cc * Cc;
    u16* xT = (u16*)d_ws;
    u16* qb = xT + sz;
    u16* kb = qb + sz;
    u16* vT = kb + sz;
    u16* wq16 = vT + sz;   // wq/wk/wv contiguous => fused [3072][1024] B matrix
    u16* wp16 = wq16 + 3 * wsz;
    int* pfx  = (int*)(wp16 + wsz);
    int* tmap = pfx + Bb * Tt;
    int* nkp  = tmap + Bb * Tt;
    u16* ob = xT;  // reuse xT region (stream-ordered)

    scan_mask<<<Bb, 256, 0, stream>>>(mask, pfx, tmap, nkp);
    cvt_w4<<<dim3((int)(wsz / 1024), 4), 256, 0, stream>>>(Wq, Wk, Wv, Wp, wq16);
    transpose_x<<<dim3(Tt / 32, Cc / 32, Bb), dim3(32, 8), 0, stream>>>(x, mask, pfx, xT);
    gemm_qkv<<<dim3(3 * Cc / 128, Bb * Tt / 128), 256, 0, stream>>>(
        xT, wq16, bq, bk, bv, nkp, qb, kb, vT);
    attn<<<dim3(Tt / 128, Bb * Hh), 256, 0, stream>>>(qb, kb, vT, tmap, nkp, ob);
    gemm_proj<<<dim3(Cc / 64, Bb * Tt / 128), 256, 0, stream>>>(ob, wp16, bp, mask, out);
    if (out_size >= Bb * Cc * Tt + Bb * Tt)
        mask_out_k<<<dim3((Bb * Tt + 255) / 256), 256, 0, stream>>>(
            mask, out + (size_t)Bb * Cc * Tt);
}